// Round 1
// baseline (2782.978 us; speedup 1.0000x reference)
//
#include <hip/hip_runtime.h>

// Sizes (fixed by the problem)
#define NXc 256
#define NQc 256
#define NUc 128
#define Bc  8192
#define NHc 512
#define EPSc 0.001f

// ---------------------------------------------------------------------------
// Tiled f32 GEMM segment: accumulates a 64x64 C-tile over K.
//   A: row-major, lda; reads A[m0+r][k]
//   BT=false: B "normal"  B[k][n]  (ldb) ; BT=true: B "transposed" B[n][k] (ldb)
// Block = 256 threads (16x16), 4x4 micro-tile per thread, BK=16.
// LDS stride 68 (=64+4): keeps float4 reads 16B-aligned, conflicts <=2-way.
// ---------------------------------------------------------------------------
template<bool BT>
__device__ inline void gemm_seg(const float* __restrict__ A, int lda,
                                const float* __restrict__ Bm, int ldb,
                                int m0, int n0, int K,
                                float acc[4][4], float* As, float* Bs)
{
    const int tid = threadIdx.x;
    const int tx = tid & 15, ty = tid >> 4;
    for (int k0 = 0; k0 < K; k0 += 16) {
        __syncthreads();   // separates previous compute from new staging
        #pragma unroll
        for (int it = 0; it < 4; ++it) {
            int idx = tid + it * 256;
            int r = idx >> 4, kk = idx & 15;
            As[kk * 68 + r] = A[(m0 + r) * lda + (k0 + kk)];
        }
        if constexpr (BT) {
            #pragma unroll
            for (int it = 0; it < 4; ++it) {
                int idx = tid + it * 256;
                int n = idx >> 4, kk = idx & 15;
                Bs[kk * 68 + n] = Bm[(n0 + n) * ldb + (k0 + kk)];
            }
        } else {
            #pragma unroll
            for (int it = 0; it < 4; ++it) {
                int idx = tid + it * 256;
                int kk = idx >> 6, n = idx & 63;
                Bs[kk * 68 + n] = Bm[(k0 + kk) * ldb + (n0 + n)];
            }
        }
        __syncthreads();
        #pragma unroll
        for (int kk = 0; kk < 16; ++kk) {
            const float4 a4 = *(const float4*)&As[kk * 68 + ty * 4];
            const float4 b4 = *(const float4*)&Bs[kk * 68 + tx * 4];
            float av[4] = {a4.x, a4.y, a4.z, a4.w};
            float bw[4] = {b4.x, b4.y, b4.z, b4.w};
            #pragma unroll
            for (int i = 0; i < 4; ++i)
                #pragma unroll
                for (int j = 0; j < 4; ++j)
                    acc[i][j] += av[i] * bw[j];
        }
    }
}

// C = alpha * S @ S^T + EPS*I   (n x n, n multiple of 64)
__global__ __launch_bounds__(256) void k_gemm_sym(const float* __restrict__ S,
                                                  float* __restrict__ C,
                                                  int n, float alpha)
{
    __shared__ __align__(16) float As[16 * 68];
    __shared__ __align__(16) float Bs[16 * 68];
    float acc[4][4] = {};
    const int m0 = blockIdx.y * 64, n0 = blockIdx.x * 64;
    gemm_seg<true>(S, n, S, n, m0, n0, n, acc, As, Bs);
    const int tx = threadIdx.x & 15, ty = threadIdx.x >> 4;
    #pragma unroll
    for (int i = 0; i < 4; ++i)
        #pragma unroll
        for (int j = 0; j < 4; ++j) {
            int r = m0 + ty * 4 + i, c = n0 + tx * 4 + j;
            float v = alpha * acc[i][j];
            if (r == c) v += EPSc;
            C[r * n + c] = v;
        }
}

// From H (512x512), Chi, Y1: build YM = [Y | M] (256x512), D11 (256x256), linv (256)
//   Y  = -0.5*(H1 + Y1 - Y1^T)           (ALPHA=0 drops the P term)
//   M  = -H2 - Chi
//   lam[q] = 0.5*H4[q][q]  -> linv = 1/lam = 2/H4diag
//   D11[i][j] = (j<i) ? -H4[i][j]/lam[i] : 0
__global__ void k_derive(const float* __restrict__ H, const float* __restrict__ Chi,
                         const float* __restrict__ Y1,
                         float* __restrict__ YM, float* __restrict__ D11,
                         float* __restrict__ linv)
{
    const int i = blockIdx.x;
    const int j = threadIdx.x;
    const float li = 2.0f / H[(256 + i) * 512 + 256 + i];
    YM[i * 512 + j] = -0.5f * (H[i * 512 + j] + Y1[i * 256 + j] - Y1[j * 256 + i]);
    YM[i * 512 + 256 + j] = -H[i * 512 + 256 + j] - Chi[i * 256 + j];
    D11[i * 256 + j] = (j < i) ? (-H[(256 + i) * 512 + 256 + j] * li) : 0.0f;
    if (j == 0) linv[i] = li;
}

// base = (xi @ Chi) * linv[col] + u @ D12^T + bv    -> basew (8192 x 256)
__global__ __launch_bounds__(256) void k_base(const float* __restrict__ xi,
                                              const float* __restrict__ u,
                                              const float* __restrict__ Chi,
                                              const float* __restrict__ D12,
                                              const float* __restrict__ bv,
                                              const float* __restrict__ linv,
                                              float* __restrict__ basew)
{
    __shared__ __align__(16) float As[16 * 68];
    __shared__ __align__(16) float Bs[16 * 68];
    float acc[4][4] = {};
    const int m0 = blockIdx.y * 64, n0 = blockIdx.x * 64;
    gemm_seg<false>(xi, 256, Chi, 256, m0, n0, 256, acc, As, Bs);
    const int tx = threadIdx.x & 15, ty = threadIdx.x >> 4;
    #pragma unroll
    for (int j = 0; j < 4; ++j) {
        float lv = linv[n0 + tx * 4 + j];
        #pragma unroll
        for (int i = 0; i < 4; ++i) acc[i][j] *= lv;
    }
    gemm_seg<true>(u, 128, D12, 128, m0, n0, 128, acc, As, Bs);
    #pragma unroll
    for (int i = 0; i < 4; ++i)
        #pragma unroll
        for (int j = 0; j < 4; ++j) {
            int r = m0 + ty * 4 + i, c = n0 + tx * 4 + j;
            basew[r * 256 + c] = acc[i][j] + bv[c];
        }
}

// In-place Gauss-Jordan inverse of 256x256 SPD matrix (no pivoting).
// One block, 1024 threads (32x32 grid), each owns an 8x8 register tile.
__global__ __launch_bounds__(1024) void k_gj(float* __restrict__ M)
{
    __shared__ float pr[256];   // pivot row (pre-update values)
    __shared__ float pc[256];   // pivot col (pre-update values)
    const int tid = threadIdx.x;
    const int tx = tid & 31, ty = tid >> 5;
    float m[8][8];
    #pragma unroll
    for (int ii = 0; ii < 8; ++ii)
        #pragma unroll
        for (int jj = 0; jj < 8; ++jj)
            m[ii][jj] = M[(ty * 8 + ii) * 256 + tx * 8 + jj];

    for (int k = 0; k < 256; ++k) {
        const int kb = k >> 3, kl = k & 7;
        if (ty == kb) {
            #pragma unroll
            for (int jj = 0; jj < 8; ++jj) pr[tx * 8 + jj] = m[kl][jj];
        }
        if (tx == kb) {
            #pragma unroll
            for (int ii = 0; ii < 8; ++ii) pc[ty * 8 + ii] = m[ii][kl];
        }
        __syncthreads();
        const float pinv = 1.0f / pr[k];
        #pragma unroll
        for (int ii = 0; ii < 8; ++ii) {
            const int i = ty * 8 + ii;
            const float fi = pc[i] * pinv;
            #pragma unroll
            for (int jj = 0; jj < 8; ++jj) {
                const int j = tx * 8 + jj;
                float v;
                if (i == k && j == k)      v = pinv;
                else if (i == k)           v = pr[j] * pinv;
                else if (j == k)           v = -fi;
                else                       v = m[ii][jj] - fi * pr[j];
                m[ii][jj] = v;
            }
        }
        __syncthreads();
    }
    #pragma unroll
    for (int ii = 0; ii < 8; ++ii)
        #pragma unroll
        for (int jj = 0; jj < 8; ++jj)
            M[(ty * 8 + ii) * 256 + tx * 8 + jj] = m[ii][jj];
}

// Sequential recurrence: w[:,i] = tanh(base[:,i] + sum_{j<i} w[:,j]*D11[i][j])
// In-place on basew. 32 rows/block, 8 lanes per row, 8 rows per wave.
// No __syncthreads in the loop: each wave owns its 8 rows; per-wave LDS in-order.
__global__ __launch_bounds__(256) void k_scan(const float* __restrict__ d11,
                                              float* __restrict__ basew)
{
    __shared__ float wls[32 * 257];
    const int tid = threadIdx.x;
    const int row0 = blockIdx.x * 32;
    for (int idx = tid; idx < 32 * 256; idx += 256) {
        int r = idx >> 8, c = idx & 255;
        wls[r * 257 + c] = basew[(row0 + r) * 256 + c];
    }
    __syncthreads();
    const int lane = tid & 63;
    const int rloc = (tid >> 6) * 8 + (lane >> 3);
    const int t = lane & 7;
    float* rowp = &wls[rloc * 257];
    for (int i = 0; i < 256; ++i) {
        float part = 0.f;
        const float* drow = d11 + i * 256;
        for (int j = t; j < i; j += 8)
            part += rowp[j] * drow[j];
        part += __shfl_xor(part, 1);
        part += __shfl_xor(part, 2);
        part += __shfl_xor(part, 4);
        const float v = rowp[i] + part;     // rowp[i] still holds base
        rowp[i] = tanhf(v);                 // all 8 lanes write same value
    }
    __syncthreads();
    for (int idx = tid; idx < 32 * 256; idx += 256) {
        int r = idx >> 8, c = idx & 255;
        basew[(row0 + r) * 256 + c] = wls[r * 257 + c];
    }
}

// AB = Pinv @ [Y | M]   (256 x 512): rows give A[x][k] and B1[x][q] directly
__global__ __launch_bounds__(256) void k_ab(const float* __restrict__ Pinv,
                                            const float* __restrict__ YM,
                                            float* __restrict__ AB)
{
    __shared__ __align__(16) float As[16 * 68];
    __shared__ __align__(16) float Bs[16 * 68];
    float acc[4][4] = {};
    const int m0 = blockIdx.y * 64, n0 = blockIdx.x * 64;
    gemm_seg<false>(Pinv, 256, YM, 512, m0, n0, 256, acc, As, Bs);
    const int tx = threadIdx.x & 15, ty = threadIdx.x >> 4;
    #pragma unroll
    for (int i = 0; i < 4; ++i)
        #pragma unroll
        for (int j = 0; j < 4; ++j)
            AB[(m0 + ty * 4 + i) * 512 + n0 + tx * 4 + j] = acc[i][j];
}

// xi_dot = xi @ A^T + w @ B1^T + u @ B2^T + bx
__global__ __launch_bounds__(256) void k_final(const float* __restrict__ xi,
                                               const float* __restrict__ w,
                                               const float* __restrict__ u,
                                               const float* __restrict__ AB,
                                               const float* __restrict__ B2,
                                               const float* __restrict__ bx,
                                               float* __restrict__ out)
{
    __shared__ __align__(16) float As[16 * 68];
    __shared__ __align__(16) float Bs[16 * 68];
    float acc[4][4] = {};
    const int m0 = blockIdx.y * 64, n0 = blockIdx.x * 64;
    gemm_seg<true>(xi, 256, AB, 512, m0, n0, 256, acc, As, Bs);        // A-part
    gemm_seg<true>(w, 256, AB + 256, 512, m0, n0, 256, acc, As, Bs);   // B1-part
    gemm_seg<true>(u, 128, B2, 128, m0, n0, 128, acc, As, Bs);         // B2-part
    const int tx = threadIdx.x & 15, ty = threadIdx.x >> 4;
    #pragma unroll
    for (int i = 0; i < 4; ++i)
        #pragma unroll
        for (int j = 0; j < 4; ++j) {
            int r = m0 + ty * 4 + i, c = n0 + tx * 4 + j;
            out[r * 256 + c] = acc[i][j] + bx[c];
        }
}

extern "C" void kernel_launch(void* const* d_in, const int* in_sizes, int n_in,
                              void* d_out, int out_size, void* d_ws, size_t ws_size,
                              hipStream_t stream)
{
    (void)in_sizes; (void)n_in; (void)out_size; (void)ws_size;
    // setup_inputs order: t, xi, u, Pstar, Chi, Y1, B2, D12, X, bx, bv
    const float* xi    = (const float*)d_in[1];
    const float* u     = (const float*)d_in[2];
    const float* Pstar = (const float*)d_in[3];
    const float* Chi   = (const float*)d_in[4];
    const float* Y1    = (const float*)d_in[5];
    const float* B2    = (const float*)d_in[6];
    const float* D12   = (const float*)d_in[7];
    const float* X     = (const float*)d_in[8];
    const float* bx    = (const float*)d_in[9];
    const float* bv    = (const float*)d_in[10];
    float* out = (float*)d_out;

    float* ws    = (float*)d_ws;
    float* H     = ws;              // 512*512   = 262144
    float* YM    = H + 262144;      // 256*512   = 131072
    float* D11   = YM + 131072;     // 256*256   =  65536
    float* linv  = D11 + 65536;     // 256
    float* Pm    = linv + 256;      // 256*256   =  65536  (becomes Pinv)
    float* AB    = Pm + 65536;      // 256*512   = 131072
    float* basew = AB + 131072;     // 8192*256  = 2097152 (base, then w in-place)

    k_gemm_sym<<<dim3(8, 8), 256, 0, stream>>>(X, H, 512, 1.0f);         // H = X X^T + eps I
    k_gemm_sym<<<dim3(4, 4), 256, 0, stream>>>(Pstar, Pm, 256, 0.5f);    // P
    k_derive  <<<dim3(256), 256, 0, stream>>>(H, Chi, Y1, YM, D11, linv);
    k_base    <<<dim3(4, 128), 256, 0, stream>>>(xi, u, Chi, D12, bv, linv, basew);
    k_gj      <<<dim3(1), 1024, 0, stream>>>(Pm);                        // Pm -> Pinv
    k_scan    <<<dim3(256), 256, 0, stream>>>(D11, basew);               // basew -> w
    k_ab      <<<dim3(8, 4), 256, 0, stream>>>(Pm, YM, AB);              // [A | B1]
    k_final   <<<dim3(4, 128), 256, 0, stream>>>(xi, basew, u, AB, B2, bx, out);
}

// Round 2
// 883.386 us; speedup vs baseline: 3.1504x; 3.1504x over previous
//
#include <hip/hip_runtime.h>

// Sizes (fixed by the problem)
#define NXc 256
#define NQc 256
#define NUc 128
#define Bc  8192
#define NHc 512
#define EPSc 0.001f

// ---------------------------------------------------------------------------
// Tiled f32 GEMM segment: accumulates a 64x64 C-tile over K.
//   A: row-major, lda; reads A[m0+r][k]
//   BT=false: B "normal"  B[k][n]  (ldb) ; BT=true: B "transposed" B[n][k] (ldb)
// Block = 256 threads (16x16), 4x4 micro-tile per thread, BK=16.
// LDS stride 68 (=64+4): keeps float4 reads 16B-aligned, conflicts <=2-way.
// ---------------------------------------------------------------------------
template<bool BT>
__device__ inline void gemm_seg(const float* __restrict__ A, int lda,
                                const float* __restrict__ Bm, int ldb,
                                int m0, int n0, int K,
                                float acc[4][4], float* As, float* Bs)
{
    const int tid = threadIdx.x;
    const int tx = tid & 15, ty = tid >> 4;
    for (int k0 = 0; k0 < K; k0 += 16) {
        __syncthreads();   // separates previous compute from new staging
        #pragma unroll
        for (int it = 0; it < 4; ++it) {
            int idx = tid + it * 256;
            int r = idx >> 4, kk = idx & 15;
            As[kk * 68 + r] = A[(m0 + r) * lda + (k0 + kk)];
        }
        if constexpr (BT) {
            #pragma unroll
            for (int it = 0; it < 4; ++it) {
                int idx = tid + it * 256;
                int n = idx >> 4, kk = idx & 15;
                Bs[kk * 68 + n] = Bm[(n0 + n) * ldb + (k0 + kk)];
            }
        } else {
            #pragma unroll
            for (int it = 0; it < 4; ++it) {
                int idx = tid + it * 256;
                int kk = idx >> 6, n = idx & 63;
                Bs[kk * 68 + n] = Bm[(k0 + kk) * ldb + (n0 + n)];
            }
        }
        __syncthreads();
        #pragma unroll
        for (int kk = 0; kk < 16; ++kk) {
            const float4 a4 = *(const float4*)&As[kk * 68 + ty * 4];
            const float4 b4 = *(const float4*)&Bs[kk * 68 + tx * 4];
            float av[4] = {a4.x, a4.y, a4.z, a4.w};
            float bw[4] = {b4.x, b4.y, b4.z, b4.w};
            #pragma unroll
            for (int i = 0; i < 4; ++i)
                #pragma unroll
                for (int j = 0; j < 4; ++j)
                    acc[i][j] += av[i] * bw[j];
        }
    }
}

// C = alpha * S @ S^T + EPS*I   (n x n, n multiple of 64)
__global__ __launch_bounds__(256) void k_gemm_sym(const float* __restrict__ S,
                                                  float* __restrict__ C,
                                                  int n, float alpha)
{
    __shared__ __align__(16) float As[16 * 68];
    __shared__ __align__(16) float Bs[16 * 68];
    float acc[4][4] = {};
    const int m0 = blockIdx.y * 64, n0 = blockIdx.x * 64;
    gemm_seg<true>(S, n, S, n, m0, n0, n, acc, As, Bs);
    const int tx = threadIdx.x & 15, ty = threadIdx.x >> 4;
    #pragma unroll
    for (int i = 0; i < 4; ++i)
        #pragma unroll
        for (int j = 0; j < 4; ++j) {
            int r = m0 + ty * 4 + i, c = n0 + tx * 4 + j;
            float v = alpha * acc[i][j];
            if (r == c) v += EPSc;
            C[r * n + c] = v;
        }
}

// From H (512x512), Chi, Y1: build YM = [Y | M] (256x512), D11 (256x256), linv (256)
__global__ void k_derive(const float* __restrict__ H, const float* __restrict__ Chi,
                         const float* __restrict__ Y1,
                         float* __restrict__ YM, float* __restrict__ D11,
                         float* __restrict__ linv)
{
    const int i = blockIdx.x;
    const int j = threadIdx.x;
    const float li = 2.0f / H[(256 + i) * 512 + 256 + i];
    YM[i * 512 + j] = -0.5f * (H[i * 512 + j] + Y1[i * 256 + j] - Y1[j * 256 + i]);
    YM[i * 512 + 256 + j] = -H[i * 512 + 256 + j] - Chi[i * 256 + j];
    D11[i * 256 + j] = (j < i) ? (-H[(256 + i) * 512 + 256 + j] * li) : 0.0f;
    if (j == 0) linv[i] = li;
}

// base = (xi @ Chi) * linv[col] + u @ D12^T + bv    -> basew (8192 x 256)
__global__ __launch_bounds__(256) void k_base(const float* __restrict__ xi,
                                              const float* __restrict__ u,
                                              const float* __restrict__ Chi,
                                              const float* __restrict__ D12,
                                              const float* __restrict__ bv,
                                              const float* __restrict__ linv,
                                              float* __restrict__ basew)
{
    __shared__ __align__(16) float As[16 * 68];
    __shared__ __align__(16) float Bs[16 * 68];
    float acc[4][4] = {};
    const int m0 = blockIdx.y * 64, n0 = blockIdx.x * 64;
    gemm_seg<false>(xi, 256, Chi, 256, m0, n0, 256, acc, As, Bs);
    const int tx = threadIdx.x & 15, ty = threadIdx.x >> 4;
    #pragma unroll
    for (int j = 0; j < 4; ++j) {
        float lv = linv[n0 + tx * 4 + j];
        #pragma unroll
        for (int i = 0; i < 4; ++i) acc[i][j] *= lv;
    }
    gemm_seg<true>(u, 128, D12, 128, m0, n0, 128, acc, As, Bs);
    #pragma unroll
    for (int i = 0; i < 4; ++i)
        #pragma unroll
        for (int j = 0; j < 4; ++j) {
            int r = m0 + ty * 4 + i, c = n0 + tx * 4 + j;
            basew[r * 256 + c] = acc[i][j] + bv[c];
        }
}

// ---------------------------------------------------------------------------
// In-place Gauss-Jordan inverse of 256x256 SPD matrix (no pivoting).
// One block, 1024 threads. Thread (tx=tid&31, ty=tid>>5) owns rows ty*8+ii,
// COLUMNS tx+32*jj (column-cyclic -> pivot-row LDS reads hit bank tx,
// 2 lanes/bank = conflict-free). Pivot column obtained via intra-wave __shfl
// (holder lane = (tid&32)|kt). One barrier per step via ping-pong pr buffer:
// owner of row k+1 stages its UPDATED row at the end of step k.
// kj loop fully unrolled so m[ii][kj] is compile-time indexed (no scratch).
// ---------------------------------------------------------------------------
__global__ __launch_bounds__(1024) void k_gj(float* __restrict__ M)
{
    __shared__ float prbuf[2][256];
    const int tid = threadIdx.x;
    const int tx = tid & 31;
    const int ty = tid >> 5;
    float m[8][8];
    #pragma unroll
    for (int ii = 0; ii < 8; ++ii)
        #pragma unroll
        for (int jj = 0; jj < 8; ++jj)
            m[ii][jj] = M[(ty * 8 + ii) * 256 + tx + 32 * jj];

    if (ty == 0) {
        #pragma unroll
        for (int jj = 0; jj < 8; ++jj) prbuf[0][tx + 32 * jj] = m[0][jj];
    }
    __syncthreads();

    #pragma unroll
    for (int kj = 0; kj < 8; ++kj) {
        #pragma unroll 1
        for (int kt = 0; kt < 32; ++kt) {
            const int k = kj * 32 + kt;
            const float* pr = prbuf[k & 1];
            float* prn = prbuf[(k + 1) & 1];
            const float pinv = 1.0f / pr[k];
            const int srcLane = (tid & 32) | kt;
            float prv[8], pcv[8];
            #pragma unroll
            for (int jj = 0; jj < 8; ++jj) prv[jj] = pr[tx + 32 * jj];
            #pragma unroll
            for (int ii = 0; ii < 8; ++ii) pcv[ii] = __shfl(m[ii][kj], srcLane);
            const bool colown = (tx == kt);
            #pragma unroll
            for (int ii = 0; ii < 8; ++ii) {
                const float fi = pcv[ii] * pinv;
                #pragma unroll
                for (int jj = 0; jj < 8; ++jj)
                    m[ii][jj] = __builtin_fmaf(-fi, prv[jj], m[ii][jj]);
                if (colown) m[ii][kj] = -fi;
            }
            if (ty == (k >> 3)) {          // row-k owner: patch pivot row
                const int kl = k & 7;
                #pragma unroll
                for (int ii = 0; ii < 8; ++ii) if (ii == kl) {
                    #pragma unroll
                    for (int jj = 0; jj < 8; ++jj) m[ii][jj] = prv[jj] * pinv;
                    if (colown) m[ii][kj] = pinv;
                }
            }
            if (ty == ((k + 1) >> 3)) {    // stage next pivot row (updated)
                const int kl1 = (k + 1) & 7;
                #pragma unroll
                for (int ii = 0; ii < 8; ++ii) if (ii == kl1) {
                    #pragma unroll
                    for (int jj = 0; jj < 8; ++jj) prn[tx + 32 * jj] = m[ii][jj];
                }
            }
            __syncthreads();
        }
    }

    #pragma unroll
    for (int ii = 0; ii < 8; ++ii)
        #pragma unroll
        for (int jj = 0; jj < 8; ++jj)
            M[(ty * 8 + ii) * 256 + tx + 32 * jj] = m[ii][jj];
}

// Sequential recurrence: w[:,i] = tanh(base[:,i] + sum_{j<i} w[:,j]*D11[i][j])
__global__ __launch_bounds__(256) void k_scan(const float* __restrict__ d11,
                                              float* __restrict__ basew)
{
    __shared__ float wls[32 * 257];
    const int tid = threadIdx.x;
    const int row0 = blockIdx.x * 32;
    for (int idx = tid; idx < 32 * 256; idx += 256) {
        int r = idx >> 8, c = idx & 255;
        wls[r * 257 + c] = basew[(row0 + r) * 256 + c];
    }
    __syncthreads();
    const int lane = tid & 63;
    const int rloc = (tid >> 6) * 8 + (lane >> 3);
    const int t = lane & 7;
    float* rowp = &wls[rloc * 257];
    for (int i = 0; i < 256; ++i) {
        float part = 0.f;
        const float* drow = d11 + i * 256;
        for (int j = t; j < i; j += 8)
            part += rowp[j] * drow[j];
        part += __shfl_xor(part, 1);
        part += __shfl_xor(part, 2);
        part += __shfl_xor(part, 4);
        const float v = rowp[i] + part;     // rowp[i] still holds base
        rowp[i] = tanhf(v);                 // all 8 lanes write same value
    }
    __syncthreads();
    for (int idx = tid; idx < 32 * 256; idx += 256) {
        int r = idx >> 8, c = idx & 255;
        basew[(row0 + r) * 256 + c] = wls[r * 257 + c];
    }
}

// AB = Pinv @ [Y | M]   (256 x 512): rows give A[x][k] and B1[x][q] directly
__global__ __launch_bounds__(256) void k_ab(const float* __restrict__ Pinv,
                                            const float* __restrict__ YM,
                                            float* __restrict__ AB)
{
    __shared__ __align__(16) float As[16 * 68];
    __shared__ __align__(16) float Bs[16 * 68];
    float acc[4][4] = {};
    const int m0 = blockIdx.y * 64, n0 = blockIdx.x * 64;
    gemm_seg<false>(Pinv, 256, YM, 512, m0, n0, 256, acc, As, Bs);
    const int tx = threadIdx.x & 15, ty = threadIdx.x >> 4;
    #pragma unroll
    for (int i = 0; i < 4; ++i)
        #pragma unroll
        for (int j = 0; j < 4; ++j)
            AB[(m0 + ty * 4 + i) * 512 + n0 + tx * 4 + j] = acc[i][j];
}

// xi_dot = xi @ A^T + w @ B1^T + u @ B2^T + bx
__global__ __launch_bounds__(256) void k_final(const float* __restrict__ xi,
                                               const float* __restrict__ w,
                                               const float* __restrict__ u,
                                               const float* __restrict__ AB,
                                               const float* __restrict__ B2,
                                               const float* __restrict__ bx,
                                               float* __restrict__ out)
{
    __shared__ __align__(16) float As[16 * 68];
    __shared__ __align__(16) float Bs[16 * 68];
    float acc[4][4] = {};
    const int m0 = blockIdx.y * 64, n0 = blockIdx.x * 64;
    gemm_seg<true>(xi, 256, AB, 512, m0, n0, 256, acc, As, Bs);        // A-part
    gemm_seg<true>(w, 256, AB + 256, 512, m0, n0, 256, acc, As, Bs);   // B1-part
    gemm_seg<true>(u, 128, B2, 128, m0, n0, 128, acc, As, Bs);         // B2-part
    const int tx = threadIdx.x & 15, ty = threadIdx.x >> 4;
    #pragma unroll
    for (int i = 0; i < 4; ++i)
        #pragma unroll
        for (int j = 0; j < 4; ++j) {
            int r = m0 + ty * 4 + i, c = n0 + tx * 4 + j;
            out[r * 256 + c] = acc[i][j] + bx[c];
        }
}

extern "C" void kernel_launch(void* const* d_in, const int* in_sizes, int n_in,
                              void* d_out, int out_size, void* d_ws, size_t ws_size,
                              hipStream_t stream)
{
    (void)in_sizes; (void)n_in; (void)out_size; (void)ws_size;
    // setup_inputs order: t, xi, u, Pstar, Chi, Y1, B2, D12, X, bx, bv
    const float* xi    = (const float*)d_in[1];
    const float* u     = (const float*)d_in[2];
    const float* Pstar = (const float*)d_in[3];
    const float* Chi   = (const float*)d_in[4];
    const float* Y1    = (const float*)d_in[5];
    const float* B2    = (const float*)d_in[6];
    const float* D12   = (const float*)d_in[7];
    const float* X     = (const float*)d_in[8];
    const float* bx    = (const float*)d_in[9];
    const float* bv    = (const float*)d_in[10];
    float* out = (float*)d_out;

    float* ws    = (float*)d_ws;
    float* H     = ws;              // 512*512   = 262144
    float* YM    = H + 262144;      // 256*512   = 131072
    float* D11   = YM + 131072;     // 256*256   =  65536
    float* linv  = D11 + 65536;     // 256
    float* Pm    = linv + 256;      // 256*256   =  65536  (becomes Pinv)
    float* AB    = Pm + 65536;      // 256*512   = 131072
    float* basew = AB + 131072;     // 8192*256  = 2097152 (base, then w in-place)

    k_gemm_sym<<<dim3(8, 8), 256, 0, stream>>>(X, H, 512, 1.0f);         // H = X X^T + eps I
    k_gemm_sym<<<dim3(4, 4), 256, 0, stream>>>(Pstar, Pm, 256, 0.5f);    // P
    k_derive  <<<dim3(256), 256, 0, stream>>>(H, Chi, Y1, YM, D11, linv);
    k_base    <<<dim3(4, 128), 256, 0, stream>>>(xi, u, Chi, D12, bv, linv, basew);
    k_gj      <<<dim3(1), 1024, 0, stream>>>(Pm);                        // Pm -> Pinv
    k_scan    <<<dim3(256), 256, 0, stream>>>(D11, basew);               // basew -> w
    k_ab      <<<dim3(8, 4), 256, 0, stream>>>(Pm, YM, AB);              // [A | B1]
    k_final   <<<dim3(4, 128), 256, 0, stream>>>(xi, basew, u, AB, B2, bx, out);
}

// Round 3
// 585.862 us; speedup vs baseline: 4.7502x; 1.5078x over previous
//
#include <hip/hip_runtime.h>

// Sizes (fixed by the problem)
#define NXc 256
#define NQc 256
#define NUc 128
#define Bc  8192
#define NHc 512
#define EPSc 0.001f

// ---------------------------------------------------------------------------
// Tiled f32 GEMM segment: accumulates a 64x64 C-tile over K.
//   A: row-major, lda; reads A[m0+r][k]
//   BT=false: B "normal"  B[k][n]  (ldb) ; BT=true: B "transposed" B[n][k] (ldb)
// Block = 256 threads (16x16), 4x4 micro-tile per thread, BK=16.
// LDS stride 68 (=64+4): keeps float4 reads 16B-aligned, conflicts <=2-way.
// ---------------------------------------------------------------------------
template<bool BT>
__device__ inline void gemm_seg(const float* __restrict__ A, int lda,
                                const float* __restrict__ Bm, int ldb,
                                int m0, int n0, int K,
                                float acc[4][4], float* As, float* Bs)
{
    const int tid = threadIdx.x;
    const int tx = tid & 15, ty = tid >> 4;
    for (int k0 = 0; k0 < K; k0 += 16) {
        __syncthreads();   // separates previous compute from new staging
        #pragma unroll
        for (int it = 0; it < 4; ++it) {
            int idx = tid + it * 256;
            int r = idx >> 4, kk = idx & 15;
            As[kk * 68 + r] = A[(m0 + r) * lda + (k0 + kk)];
        }
        if constexpr (BT) {
            #pragma unroll
            for (int it = 0; it < 4; ++it) {
                int idx = tid + it * 256;
                int n = idx >> 4, kk = idx & 15;
                Bs[kk * 68 + n] = Bm[(n0 + n) * ldb + (k0 + kk)];
            }
        } else {
            #pragma unroll
            for (int it = 0; it < 4; ++it) {
                int idx = tid + it * 256;
                int kk = idx >> 6, n = idx & 63;
                Bs[kk * 68 + n] = Bm[(k0 + kk) * ldb + (n0 + n)];
            }
        }
        __syncthreads();
        #pragma unroll
        for (int kk = 0; kk < 16; ++kk) {
            const float4 a4 = *(const float4*)&As[kk * 68 + ty * 4];
            const float4 b4 = *(const float4*)&Bs[kk * 68 + tx * 4];
            float av[4] = {a4.x, a4.y, a4.z, a4.w};
            float bw[4] = {b4.x, b4.y, b4.z, b4.w};
            #pragma unroll
            for (int i = 0; i < 4; ++i)
                #pragma unroll
                for (int j = 0; j < 4; ++j)
                    acc[i][j] += av[i] * bw[j];
        }
    }
}

// C = alpha * S @ S^T + EPS*I   (n x n, n multiple of 64)
__global__ __launch_bounds__(256) void k_gemm_sym(const float* __restrict__ S,
                                                  float* __restrict__ C,
                                                  int n, float alpha)
{
    __shared__ __align__(16) float As[16 * 68];
    __shared__ __align__(16) float Bs[16 * 68];
    float acc[4][4] = {};
    const int m0 = blockIdx.y * 64, n0 = blockIdx.x * 64;
    gemm_seg<true>(S, n, S, n, m0, n0, n, acc, As, Bs);
    const int tx = threadIdx.x & 15, ty = threadIdx.x >> 4;
    #pragma unroll
    for (int i = 0; i < 4; ++i)
        #pragma unroll
        for (int j = 0; j < 4; ++j) {
            int r = m0 + ty * 4 + i, c = n0 + tx * 4 + j;
            float v = alpha * acc[i][j];
            if (r == c) v += EPSc;
            C[r * n + c] = v;
        }
}

// From H (512x512), Chi, Y1: build YM = [Y | M] (256x512), D11 (256x256), linv (256)
__global__ void k_derive(const float* __restrict__ H, const float* __restrict__ Chi,
                         const float* __restrict__ Y1,
                         float* __restrict__ YM, float* __restrict__ D11,
                         float* __restrict__ linv)
{
    const int i = blockIdx.x;
    const int j = threadIdx.x;
    const float li = 2.0f / H[(256 + i) * 512 + 256 + i];
    YM[i * 512 + j] = -0.5f * (H[i * 512 + j] + Y1[i * 256 + j] - Y1[j * 256 + i]);
    YM[i * 512 + 256 + j] = -H[i * 512 + 256 + j] - Chi[i * 256 + j];
    D11[i * 256 + j] = (j < i) ? (-H[(256 + i) * 512 + 256 + j] * li) : 0.0f;
    if (j == 0) linv[i] = li;
}

// base = (xi @ Chi) * linv[col] + u @ D12^T + bv    -> basew (8192 x 256)
__global__ __launch_bounds__(256) void k_base(const float* __restrict__ xi,
                                              const float* __restrict__ u,
                                              const float* __restrict__ Chi,
                                              const float* __restrict__ D12,
                                              const float* __restrict__ bv,
                                              const float* __restrict__ linv,
                                              float* __restrict__ basew)
{
    __shared__ __align__(16) float As[16 * 68];
    __shared__ __align__(16) float Bs[16 * 68];
    float acc[4][4] = {};
    const int m0 = blockIdx.y * 64, n0 = blockIdx.x * 64;
    gemm_seg<false>(xi, 256, Chi, 256, m0, n0, 256, acc, As, Bs);
    const int tx = threadIdx.x & 15, ty = threadIdx.x >> 4;
    #pragma unroll
    for (int j = 0; j < 4; ++j) {
        float lv = linv[n0 + tx * 4 + j];
        #pragma unroll
        for (int i = 0; i < 4; ++i) acc[i][j] *= lv;
    }
    gemm_seg<true>(u, 128, D12, 128, m0, n0, 128, acc, As, Bs);
    #pragma unroll
    for (int i = 0; i < 4; ++i)
        #pragma unroll
        for (int j = 0; j < 4; ++j) {
            int r = m0 + ty * 4 + i, c = n0 + tx * 4 + j;
            basew[r * 256 + c] = acc[i][j] + bv[c];
        }
}

// ---------------------------------------------------------------------------
// In-place Gauss-Jordan inverse of 256x256 SPD matrix (no pivoting).
// Column-cyclic ownership; pivot column via __shfl; 1 barrier/step.
// ---------------------------------------------------------------------------
__global__ __launch_bounds__(1024) void k_gj(float* __restrict__ M)
{
    __shared__ float prbuf[2][256];
    const int tid = threadIdx.x;
    const int tx = tid & 31;
    const int ty = tid >> 5;
    float m[8][8];
    #pragma unroll
    for (int ii = 0; ii < 8; ++ii)
        #pragma unroll
        for (int jj = 0; jj < 8; ++jj)
            m[ii][jj] = M[(ty * 8 + ii) * 256 + tx + 32 * jj];

    if (ty == 0) {
        #pragma unroll
        for (int jj = 0; jj < 8; ++jj) prbuf[0][tx + 32 * jj] = m[0][jj];
    }
    __syncthreads();

    #pragma unroll
    for (int kj = 0; kj < 8; ++kj) {
        #pragma unroll 1
        for (int kt = 0; kt < 32; ++kt) {
            const int k = kj * 32 + kt;
            const float* pr = prbuf[k & 1];
            float* prn = prbuf[(k + 1) & 1];
            const float pinv = 1.0f / pr[k];
            const int srcLane = (tid & 32) | kt;
            float prv[8], pcv[8];
            #pragma unroll
            for (int jj = 0; jj < 8; ++jj) prv[jj] = pr[tx + 32 * jj];
            #pragma unroll
            for (int ii = 0; ii < 8; ++ii) pcv[ii] = __shfl(m[ii][kj], srcLane);
            const bool colown = (tx == kt);
            #pragma unroll
            for (int ii = 0; ii < 8; ++ii) {
                const float fi = pcv[ii] * pinv;
                #pragma unroll
                for (int jj = 0; jj < 8; ++jj)
                    m[ii][jj] = __builtin_fmaf(-fi, prv[jj], m[ii][jj]);
                if (colown) m[ii][kj] = -fi;
            }
            if (ty == (k >> 3)) {          // row-k owner: patch pivot row
                const int kl = k & 7;
                #pragma unroll
                for (int ii = 0; ii < 8; ++ii) if (ii == kl) {
                    #pragma unroll
                    for (int jj = 0; jj < 8; ++jj) m[ii][jj] = prv[jj] * pinv;
                    if (colown) m[ii][kj] = pinv;
                }
            }
            if (ty == ((k + 1) >> 3)) {    // stage next pivot row (updated)
                const int kl1 = (k + 1) & 7;
                #pragma unroll
                for (int ii = 0; ii < 8; ++ii) if (ii == kl1) {
                    #pragma unroll
                    for (int jj = 0; jj < 8; ++jj) prn[tx + 32 * jj] = m[ii][jj];
                }
            }
            __syncthreads();
        }
    }

    #pragma unroll
    for (int ii = 0; ii < 8; ++ii)
        #pragma unroll
        for (int jj = 0; jj < 8; ++jj)
            M[(ty * 8 + ii) * 256 + tx + 32 * jj] = m[ii][jj];
}

// ---------------------------------------------------------------------------
// Blocked nonlinear forward substitution:
//   w[:,i] = tanh(base[:,i] + sum_{j<i} w[:,j]*D11[i][j])
// 32 batch-rows per block; each wave owns 8 rows (no barriers in main loop).
// Lane layout: rg=lane>>3 (row in wave), t=lane&7 (owns columns i ≡ t mod 8).
// Per column-block c of 32: dense float4 phase computes s_i = Σ_{j<32c} w_j D[i,j]
// into the owner lane's registers; then a fully-unrolled 32-step serial phase
// keeps this block's w in owner-lane registers: chain = FMA + 3 shfl + tanh.
// tanh(x) = 1 - 2/(exp(2x)+1) via fast __expf (no library call on the chain).
// ---------------------------------------------------------------------------
#define WPAD 264
__global__ __launch_bounds__(256) void k_scan(const float* __restrict__ d11,
                                              float* __restrict__ basew)
{
    __shared__ __align__(16) float wls[32 * WPAD];
    const int tid = threadIdx.x;
    const int row0 = blockIdx.x * 32;
    for (int idx = tid; idx < 32 * 64; idx += 256) {
        int r = idx >> 6, c4 = idx & 63;
        *(float4*)&wls[r * WPAD + c4 * 4] =
            *(const float4*)&basew[(row0 + r) * 256 + c4 * 4];
    }
    __syncthreads();

    const int lane = tid & 63;
    const int wv = tid >> 6;
    const int t = lane & 7;            // owns i with (i & 7) == t
    const int rg = lane >> 3;          // row within wave
    const int r = wv * 8 + rg;
    float* rowp = &wls[r * WPAD];

    #pragma unroll 1
    for (int c = 0; c < 8; ++c) {
        const int jend = 32 * c;
        const int i0 = 32 * c;
        // ---- dense phase: s[u] = sum_{j<jend} w[j] * D11[i0+8u+t][j]
        float s[4] = {0.f, 0.f, 0.f, 0.f};
        {
            const float* d0 = d11 + (i0 + t) * 256;
            for (int j = 0; j < jend; j += 4) {
                const float4 w4 = *(const float4*)&rowp[j];
                #pragma unroll
                for (int u = 0; u < 4; ++u) {
                    const float4 dv = *(const float4*)&d0[u * 8 * 256 + j];
                    s[u] = __builtin_fmaf(w4.x, dv.x, s[u]);
                    s[u] = __builtin_fmaf(w4.y, dv.y, s[u]);
                    s[u] = __builtin_fmaf(w4.z, dv.z, s[u]);
                    s[u] = __builtin_fmaf(w4.w, dv.w, s[u]);
                }
            }
        }
        // ---- preload base for owned columns (off-chain LDS reads)
        float bs[4];
        #pragma unroll
        for (int u = 0; u < 4; ++u) bs[u] = rowp[i0 + 8 * u + t];
        // ---- serial phase: 32 steps, fully unrolled (static reg indices)
        float wown[4] = {0.f, 0.f, 0.f, 0.f};
        #pragma unroll
        for (int ii = 0; ii < 32; ++ii) {
            const int i = i0 + ii;
            const float* di = d11 + i * 256 + i0;
            float part = 0.f;
            #pragma unroll
            for (int u = 0; u < 4; ++u) {
                const int jj = 8 * u + t;
                if (jj < ii) part = __builtin_fmaf(wown[u], di[jj], part);
            }
            part += __shfl_xor(part, 1);
            part += __shfl_xor(part, 2);
            part += __shfl_xor(part, 4);
            if (t == (ii & 7)) {
                const int uo = ii >> 3;
                const float x = bs[uo] + s[uo] + part;
                const float v = 1.0f - 2.0f / (__expf(2.0f * x) + 1.0f);
                wown[uo] = v;
                rowp[i] = v;           // for future dense phases (off-chain)
            }
        }
    }

    __syncthreads();
    for (int idx = tid; idx < 32 * 64; idx += 256) {
        int rr = idx >> 6, c4 = idx & 63;
        *(float4*)&basew[(row0 + rr) * 256 + c4 * 4] =
            *(const float4*)&wls[rr * WPAD + c4 * 4];
    }
}

// AB = Pinv @ [Y | M]   (256 x 512): rows give A[x][k] and B1[x][q] directly
__global__ __launch_bounds__(256) void k_ab(const float* __restrict__ Pinv,
                                            const float* __restrict__ YM,
                                            float* __restrict__ AB)
{
    __shared__ __align__(16) float As[16 * 68];
    __shared__ __align__(16) float Bs[16 * 68];
    float acc[4][4] = {};
    const int m0 = blockIdx.y * 64, n0 = blockIdx.x * 64;
    gemm_seg<false>(Pinv, 256, YM, 512, m0, n0, 256, acc, As, Bs);
    const int tx = threadIdx.x & 15, ty = threadIdx.x >> 4;
    #pragma unroll
    for (int i = 0; i < 4; ++i)
        #pragma unroll
        for (int j = 0; j < 4; ++j)
            AB[(m0 + ty * 4 + i) * 512 + n0 + tx * 4 + j] = acc[i][j];
}

// xi_dot = xi @ A^T + w @ B1^T + u @ B2^T + bx
__global__ __launch_bounds__(256) void k_final(const float* __restrict__ xi,
                                               const float* __restrict__ w,
                                               const float* __restrict__ u,
                                               const float* __restrict__ AB,
                                               const float* __restrict__ B2,
                                               const float* __restrict__ bx,
                                               float* __restrict__ out)
{
    __shared__ __align__(16) float As[16 * 68];
    __shared__ __align__(16) float Bs[16 * 68];
    float acc[4][4] = {};
    const int m0 = blockIdx.y * 64, n0 = blockIdx.x * 64;
    gemm_seg<true>(xi, 256, AB, 512, m0, n0, 256, acc, As, Bs);        // A-part
    gemm_seg<true>(w, 256, AB + 256, 512, m0, n0, 256, acc, As, Bs);   // B1-part
    gemm_seg<true>(u, 128, B2, 128, m0, n0, 128, acc, As, Bs);         // B2-part
    const int tx = threadIdx.x & 15, ty = threadIdx.x >> 4;
    #pragma unroll
    for (int i = 0; i < 4; ++i)
        #pragma unroll
        for (int j = 0; j < 4; ++j) {
            int r = m0 + ty * 4 + i, c = n0 + tx * 4 + j;
            out[r * 256 + c] = acc[i][j] + bx[c];
        }
}

extern "C" void kernel_launch(void* const* d_in, const int* in_sizes, int n_in,
                              void* d_out, int out_size, void* d_ws, size_t ws_size,
                              hipStream_t stream)
{
    (void)in_sizes; (void)n_in; (void)out_size; (void)ws_size;
    // setup_inputs order: t, xi, u, Pstar, Chi, Y1, B2, D12, X, bx, bv
    const float* xi    = (const float*)d_in[1];
    const float* u     = (const float*)d_in[2];
    const float* Pstar = (const float*)d_in[3];
    const float* Chi   = (const float*)d_in[4];
    const float* Y1    = (const float*)d_in[5];
    const float* B2    = (const float*)d_in[6];
    const float* D12   = (const float*)d_in[7];
    const float* X     = (const float*)d_in[8];
    const float* bx    = (const float*)d_in[9];
    const float* bv    = (const float*)d_in[10];
    float* out = (float*)d_out;

    float* ws    = (float*)d_ws;
    float* H     = ws;              // 512*512   = 262144
    float* YM    = H + 262144;      // 256*512   = 131072
    float* D11   = YM + 131072;     // 256*256   =  65536
    float* linv  = D11 + 65536;     // 256
    float* Pm    = linv + 256;      // 256*256   =  65536  (becomes Pinv)
    float* AB    = Pm + 65536;      // 256*512   = 131072
    float* basew = AB + 131072;     // 8192*256  = 2097152 (base, then w in-place)

    k_gemm_sym<<<dim3(8, 8), 256, 0, stream>>>(X, H, 512, 1.0f);         // H = X X^T + eps I
    k_gemm_sym<<<dim3(4, 4), 256, 0, stream>>>(Pstar, Pm, 256, 0.5f);    // P
    k_derive  <<<dim3(256), 256, 0, stream>>>(H, Chi, Y1, YM, D11, linv);
    k_base    <<<dim3(4, 128), 256, 0, stream>>>(xi, u, Chi, D12, bv, linv, basew);
    k_gj      <<<dim3(1), 1024, 0, stream>>>(Pm);                        // Pm -> Pinv
    k_scan    <<<dim3(256), 256, 0, stream>>>(D11, basew);               // basew -> w
    k_ab      <<<dim3(8, 4), 256, 0, stream>>>(Pm, YM, AB);              // [A | B1]
    k_final   <<<dim3(4, 128), 256, 0, stream>>>(xi, basew, u, AB, B2, bx, out);
}

// Round 4
// 569.262 us; speedup vs baseline: 4.8887x; 1.0292x over previous
//
#include <hip/hip_runtime.h>

// Sizes (fixed by the problem)
#define NXc 256
#define NQc 256
#define NUc 128
#define Bc  8192
#define NHc 512
#define EPSc 0.001f

// ---------------------------------------------------------------------------
// Tiled f32 GEMM segment v2: accumulates a 64x64 C-tile over K.
//   A: row-major, lda; reads A[m0+r][k]
//   BT=false: B "normal"  B[k][n]  (ldb) ; BT=true: B "transposed" B[n][k] (ldb)
// Block = 256 threads (16x16), 4x4 micro-tile, BK=32 (half the barriers of v1).
// Global loads are float4 (coalesced 128B per 8-lane group); A (and B when BT)
// are transpose-written to LDS As[k][m] via 4x b32 scatter so the compute
// phase reads both operands as b128. LDS stride 68: b128 reads 16B-aligned,
// read conflicts <=2-way (free), A-write 4-way (8 writes per 512 FMA, ok).
// ---------------------------------------------------------------------------
template<bool BT>
__device__ inline void gemm_seg(const float* __restrict__ A, int lda,
                                const float* __restrict__ Bm, int ldb,
                                int m0, int n0, int K,
                                float acc[4][4], float* As, float* Bs)
{
    const int tid = threadIdx.x;
    const int tx = tid & 15, ty = tid >> 4;
    const int ar  = tid >> 3;     // 0..31 (+32 on second pass)
    const int akc = tid & 7;      // float4 index along k
    for (int k0 = 0; k0 < K; k0 += 32) {
        __syncthreads();   // separates previous compute from new staging
        // ---- stage A: 64 rows x 32 k, transpose-write to As[k][m]
        #pragma unroll
        for (int it = 0; it < 2; ++it) {
            const int r = ar + it * 32;
            const float4 a4 = *(const float4*)&A[(m0 + r) * lda + k0 + akc * 4];
            As[(akc * 4 + 0) * 68 + r] = a4.x;
            As[(akc * 4 + 1) * 68 + r] = a4.y;
            As[(akc * 4 + 2) * 68 + r] = a4.z;
            As[(akc * 4 + 3) * 68 + r] = a4.w;
        }
        // ---- stage B
        if constexpr (BT) {
            #pragma unroll
            for (int it = 0; it < 2; ++it) {
                const int n = ar + it * 32;
                const float4 b4 = *(const float4*)&Bm[(n0 + n) * ldb + k0 + akc * 4];
                Bs[(akc * 4 + 0) * 68 + n] = b4.x;
                Bs[(akc * 4 + 1) * 68 + n] = b4.y;
                Bs[(akc * 4 + 2) * 68 + n] = b4.z;
                Bs[(akc * 4 + 3) * 68 + n] = b4.w;
            }
        } else {
            const int bn4 = tid & 15;   // n = bn4*4
            const int bk  = tid >> 4;   // 0..15 (+16 on second pass)
            #pragma unroll
            for (int it = 0; it < 2; ++it) {
                const int kk = bk + it * 16;
                *(float4*)&Bs[kk * 68 + bn4 * 4] =
                    *(const float4*)&Bm[(k0 + kk) * ldb + n0 + bn4 * 4];
            }
        }
        __syncthreads();
        // ---- compute: 32 k-steps, both operands b128
        #pragma unroll
        for (int kk = 0; kk < 32; ++kk) {
            const float4 a4 = *(const float4*)&As[kk * 68 + ty * 4];
            const float4 b4 = *(const float4*)&Bs[kk * 68 + tx * 4];
            const float av[4] = {a4.x, a4.y, a4.z, a4.w};
            const float bw[4] = {b4.x, b4.y, b4.z, b4.w};
            #pragma unroll
            for (int i = 0; i < 4; ++i)
                #pragma unroll
                for (int j = 0; j < 4; ++j)
                    acc[i][j] = __builtin_fmaf(av[i], bw[j], acc[i][j]);
        }
    }
}

// C = alpha * S @ S^T + EPS*I   (n x n, n multiple of 64)
__global__ __launch_bounds__(256) void k_gemm_sym(const float* __restrict__ S,
                                                  float* __restrict__ C,
                                                  int n, float alpha)
{
    __shared__ __align__(16) float As[32 * 68];
    __shared__ __align__(16) float Bs[32 * 68];
    float acc[4][4] = {};
    const int m0 = blockIdx.y * 64, n0 = blockIdx.x * 64;
    gemm_seg<true>(S, n, S, n, m0, n0, n, acc, As, Bs);
    const int tx = threadIdx.x & 15, ty = threadIdx.x >> 4;
    #pragma unroll
    for (int i = 0; i < 4; ++i)
        #pragma unroll
        for (int j = 0; j < 4; ++j) {
            int r = m0 + ty * 4 + i, c = n0 + tx * 4 + j;
            float v = alpha * acc[i][j];
            if (r == c) v += EPSc;
            C[r * n + c] = v;
        }
}

// From H (512x512), Chi, Y1: build YM = [Y | M] (256x512), D11 (256x256), linv (256)
__global__ void k_derive(const float* __restrict__ H, const float* __restrict__ Chi,
                         const float* __restrict__ Y1,
                         float* __restrict__ YM, float* __restrict__ D11,
                         float* __restrict__ linv)
{
    const int i = blockIdx.x;
    const int j = threadIdx.x;
    const float li = 2.0f / H[(256 + i) * 512 + 256 + i];
    YM[i * 512 + j] = -0.5f * (H[i * 512 + j] + Y1[i * 256 + j] - Y1[j * 256 + i]);
    YM[i * 512 + 256 + j] = -H[i * 512 + 256 + j] - Chi[i * 256 + j];
    D11[i * 256 + j] = (j < i) ? (-H[(256 + i) * 512 + 256 + j] * li) : 0.0f;
    if (j == 0) linv[i] = li;
}

// base = (xi @ Chi) * linv[col] + u @ D12^T + bv    -> basew (8192 x 256)
__global__ __launch_bounds__(256) void k_base(const float* __restrict__ xi,
                                              const float* __restrict__ u,
                                              const float* __restrict__ Chi,
                                              const float* __restrict__ D12,
                                              const float* __restrict__ bv,
                                              const float* __restrict__ linv,
                                              float* __restrict__ basew)
{
    __shared__ __align__(16) float As[32 * 68];
    __shared__ __align__(16) float Bs[32 * 68];
    float acc[4][4] = {};
    const int m0 = blockIdx.y * 64, n0 = blockIdx.x * 64;
    gemm_seg<false>(xi, 256, Chi, 256, m0, n0, 256, acc, As, Bs);
    const int tx = threadIdx.x & 15, ty = threadIdx.x >> 4;
    #pragma unroll
    for (int j = 0; j < 4; ++j) {
        float lv = linv[n0 + tx * 4 + j];
        #pragma unroll
        for (int i = 0; i < 4; ++i) acc[i][j] *= lv;
    }
    gemm_seg<true>(u, 128, D12, 128, m0, n0, 128, acc, As, Bs);
    #pragma unroll
    for (int i = 0; i < 4; ++i)
        #pragma unroll
        for (int j = 0; j < 4; ++j) {
            int r = m0 + ty * 4 + i, c = n0 + tx * 4 + j;
            basew[r * 256 + c] = acc[i][j] + bv[c];
        }
}

// ---------------------------------------------------------------------------
// In-place Gauss-Jordan inverse of 256x256 SPD matrix (no pivoting).
// Column-cyclic ownership; pivot column via __shfl; 1 barrier/step.
// ---------------------------------------------------------------------------
__global__ __launch_bounds__(1024) void k_gj(float* __restrict__ M)
{
    __shared__ float prbuf[2][256];
    const int tid = threadIdx.x;
    const int tx = tid & 31;
    const int ty = tid >> 5;
    float m[8][8];
    #pragma unroll
    for (int ii = 0; ii < 8; ++ii)
        #pragma unroll
        for (int jj = 0; jj < 8; ++jj)
            m[ii][jj] = M[(ty * 8 + ii) * 256 + tx + 32 * jj];

    if (ty == 0) {
        #pragma unroll
        for (int jj = 0; jj < 8; ++jj) prbuf[0][tx + 32 * jj] = m[0][jj];
    }
    __syncthreads();

    #pragma unroll
    for (int kj = 0; kj < 8; ++kj) {
        #pragma unroll 1
        for (int kt = 0; kt < 32; ++kt) {
            const int k = kj * 32 + kt;
            const float* pr = prbuf[k & 1];
            float* prn = prbuf[(k + 1) & 1];
            const float pinv = 1.0f / pr[k];
            const int srcLane = (tid & 32) | kt;
            float prv[8], pcv[8];
            #pragma unroll
            for (int jj = 0; jj < 8; ++jj) prv[jj] = pr[tx + 32 * jj];
            #pragma unroll
            for (int ii = 0; ii < 8; ++ii) pcv[ii] = __shfl(m[ii][kj], srcLane);
            const bool colown = (tx == kt);
            #pragma unroll
            for (int ii = 0; ii < 8; ++ii) {
                const float fi = pcv[ii] * pinv;
                #pragma unroll
                for (int jj = 0; jj < 8; ++jj)
                    m[ii][jj] = __builtin_fmaf(-fi, prv[jj], m[ii][jj]);
                if (colown) m[ii][kj] = -fi;
            }
            if (ty == (k >> 3)) {          // row-k owner: patch pivot row
                const int kl = k & 7;
                #pragma unroll
                for (int ii = 0; ii < 8; ++ii) if (ii == kl) {
                    #pragma unroll
                    for (int jj = 0; jj < 8; ++jj) m[ii][jj] = prv[jj] * pinv;
                    if (colown) m[ii][kj] = pinv;
                }
            }
            if (ty == ((k + 1) >> 3)) {    // stage next pivot row (updated)
                const int kl1 = (k + 1) & 7;
                #pragma unroll
                for (int ii = 0; ii < 8; ++ii) if (ii == kl1) {
                    #pragma unroll
                    for (int jj = 0; jj < 8; ++jj) prn[tx + 32 * jj] = m[ii][jj];
                }
            }
            __syncthreads();
        }
    }

    #pragma unroll
    for (int ii = 0; ii < 8; ++ii)
        #pragma unroll
        for (int jj = 0; jj < 8; ++jj)
            M[(ty * 8 + ii) * 256 + tx + 32 * jj] = m[ii][jj];
}

// ---------------------------------------------------------------------------
// Blocked nonlinear forward substitution:
//   w[:,i] = tanh(base[:,i] + sum_{j<i} w[:,j]*D11[i][j])
// ---------------------------------------------------------------------------
#define WPAD 264
__global__ __launch_bounds__(256) void k_scan(const float* __restrict__ d11,
                                              float* __restrict__ basew)
{
    __shared__ __align__(16) float wls[32 * WPAD];
    const int tid = threadIdx.x;
    const int row0 = blockIdx.x * 32;
    for (int idx = tid; idx < 32 * 64; idx += 256) {
        int r = idx >> 6, c4 = idx & 63;
        *(float4*)&wls[r * WPAD + c4 * 4] =
            *(const float4*)&basew[(row0 + r) * 256 + c4 * 4];
    }
    __syncthreads();

    const int lane = tid & 63;
    const int wv = tid >> 6;
    const int t = lane & 7;            // owns i with (i & 7) == t
    const int rg = lane >> 3;          // row within wave
    const int r = wv * 8 + rg;
    float* rowp = &wls[r * WPAD];

    #pragma unroll 1
    for (int c = 0; c < 8; ++c) {
        const int jend = 32 * c;
        const int i0 = 32 * c;
        // ---- dense phase: s[u] = sum_{j<jend} w[j] * D11[i0+8u+t][j]
        float s[4] = {0.f, 0.f, 0.f, 0.f};
        {
            const float* d0 = d11 + (i0 + t) * 256;
            for (int j = 0; j < jend; j += 4) {
                const float4 w4 = *(const float4*)&rowp[j];
                #pragma unroll
                for (int u = 0; u < 4; ++u) {
                    const float4 dv = *(const float4*)&d0[u * 8 * 256 + j];
                    s[u] = __builtin_fmaf(w4.x, dv.x, s[u]);
                    s[u] = __builtin_fmaf(w4.y, dv.y, s[u]);
                    s[u] = __builtin_fmaf(w4.z, dv.z, s[u]);
                    s[u] = __builtin_fmaf(w4.w, dv.w, s[u]);
                }
            }
        }
        // ---- preload base for owned columns (off-chain LDS reads)
        float bs[4];
        #pragma unroll
        for (int u = 0; u < 4; ++u) bs[u] = rowp[i0 + 8 * u + t];
        // ---- serial phase: 32 steps, fully unrolled (static reg indices)
        float wown[4] = {0.f, 0.f, 0.f, 0.f};
        #pragma unroll
        for (int ii = 0; ii < 32; ++ii) {
            const int i = i0 + ii;
            const float* di = d11 + i * 256 + i0;
            float part = 0.f;
            #pragma unroll
            for (int u = 0; u < 4; ++u) {
                const int jj = 8 * u + t;
                if (jj < ii) part = __builtin_fmaf(wown[u], di[jj], part);
            }
            part += __shfl_xor(part, 1);
            part += __shfl_xor(part, 2);
            part += __shfl_xor(part, 4);
            if (t == (ii & 7)) {
                const int uo = ii >> 3;
                const float x = bs[uo] + s[uo] + part;
                const float v = 1.0f - 2.0f / (__expf(2.0f * x) + 1.0f);
                wown[uo] = v;
                rowp[i] = v;           // for future dense phases (off-chain)
            }
        }
    }

    __syncthreads();
    for (int idx = tid; idx < 32 * 64; idx += 256) {
        int rr = idx >> 6, c4 = idx & 63;
        *(float4*)&basew[(row0 + rr) * 256 + c4 * 4] =
            *(const float4*)&wls[rr * WPAD + c4 * 4];
    }
}

// AB = Pinv @ [Y | M]   (256 x 512): rows give A[x][k] and B1[x][q] directly
__global__ __launch_bounds__(256) void k_ab(const float* __restrict__ Pinv,
                                            const float* __restrict__ YM,
                                            float* __restrict__ AB)
{
    __shared__ __align__(16) float As[32 * 68];
    __shared__ __align__(16) float Bs[32 * 68];
    float acc[4][4] = {};
    const int m0 = blockIdx.y * 64, n0 = blockIdx.x * 64;
    gemm_seg<false>(Pinv, 256, YM, 512, m0, n0, 256, acc, As, Bs);
    const int tx = threadIdx.x & 15, ty = threadIdx.x >> 4;
    #pragma unroll
    for (int i = 0; i < 4; ++i)
        #pragma unroll
        for (int j = 0; j < 4; ++j)
            AB[(m0 + ty * 4 + i) * 512 + n0 + tx * 4 + j] = acc[i][j];
}

// xi_dot = xi @ A^T + w @ B1^T + u @ B2^T + bx
__global__ __launch_bounds__(256) void k_final(const float* __restrict__ xi,
                                               const float* __restrict__ w,
                                               const float* __restrict__ u,
                                               const float* __restrict__ AB,
                                               const float* __restrict__ B2,
                                               const float* __restrict__ bx,
                                               float* __restrict__ out)
{
    __shared__ __align__(16) float As[32 * 68];
    __shared__ __align__(16) float Bs[32 * 68];
    float acc[4][4] = {};
    const int m0 = blockIdx.y * 64, n0 = blockIdx.x * 64;
    gemm_seg<true>(xi, 256, AB, 512, m0, n0, 256, acc, As, Bs);        // A-part
    gemm_seg<true>(w, 256, AB + 256, 512, m0, n0, 256, acc, As, Bs);   // B1-part
    gemm_seg<true>(u, 128, B2, 128, m0, n0, 128, acc, As, Bs);         // B2-part
    const int tx = threadIdx.x & 15, ty = threadIdx.x >> 4;
    #pragma unroll
    for (int i = 0; i < 4; ++i)
        #pragma unroll
        for (int j = 0; j < 4; ++j) {
            int r = m0 + ty * 4 + i, c = n0 + tx * 4 + j;
            out[r * 256 + c] = acc[i][j] + bx[c];
        }
}

extern "C" void kernel_launch(void* const* d_in, const int* in_sizes, int n_in,
                              void* d_out, int out_size, void* d_ws, size_t ws_size,
                              hipStream_t stream)
{
    (void)in_sizes; (void)n_in; (void)out_size; (void)ws_size;
    // setup_inputs order: t, xi, u, Pstar, Chi, Y1, B2, D12, X, bx, bv
    const float* xi    = (const float*)d_in[1];
    const float* u     = (const float*)d_in[2];
    const float* Pstar = (const float*)d_in[3];
    const float* Chi   = (const float*)d_in[4];
    const float* Y1    = (const float*)d_in[5];
    const float* B2    = (const float*)d_in[6];
    const float* D12   = (const float*)d_in[7];
    const float* X     = (const float*)d_in[8];
    const float* bx    = (const float*)d_in[9];
    const float* bv    = (const float*)d_in[10];
    float* out = (float*)d_out;

    float* ws    = (float*)d_ws;
    float* H     = ws;              // 512*512   = 262144
    float* YM    = H + 262144;      // 256*512   = 131072
    float* D11   = YM + 131072;     // 256*256   =  65536
    float* linv  = D11 + 65536;     // 256
    float* Pm    = linv + 256;      // 256*256   =  65536  (becomes Pinv)
    float* AB    = Pm + 65536;      // 256*512   = 131072
    float* basew = AB + 131072;     // 8192*256  = 2097152 (base, then w in-place)

    k_gemm_sym<<<dim3(8, 8), 256, 0, stream>>>(X, H, 512, 1.0f);         // H = X X^T + eps I
    k_gemm_sym<<<dim3(4, 4), 256, 0, stream>>>(Pstar, Pm, 256, 0.5f);    // P
    k_derive  <<<dim3(256), 256, 0, stream>>>(H, Chi, Y1, YM, D11, linv);
    k_base    <<<dim3(4, 128), 256, 0, stream>>>(xi, u, Chi, D12, bv, linv, basew);
    k_gj      <<<dim3(1), 1024, 0, stream>>>(Pm);                        // Pm -> Pinv
    k_scan    <<<dim3(256), 256, 0, stream>>>(D11, basew);               // basew -> w
    k_ab      <<<dim3(8, 4), 256, 0, stream>>>(Pm, YM, AB);              // [A | B1]
    k_final   <<<dim3(4, 128), 256, 0, stream>>>(xi, basew, u, AB, B2, bx, out);
}

// Round 5
// 492.881 us; speedup vs baseline: 5.6464x; 1.1550x over previous
//
#include <hip/hip_runtime.h>

// Sizes (fixed by the problem)
#define NXc 256
#define NQc 256
#define NUc 128
#define Bc  8192
#define NHc 512
#define EPSc 0.001f

// ---------------------------------------------------------------------------
// Tiled f32 GEMM segment v2: accumulates a 64x64 C-tile over K.
//   A: row-major, lda; reads A[m0+r][k]
//   BT=false: B "normal"  B[k][n]  (ldb) ; BT=true: B "transposed" B[n][k] (ldb)
// Block = 256 threads (16x16), 4x4 micro-tile, BK=32.
// ---------------------------------------------------------------------------
template<bool BT>
__device__ inline void gemm_seg(const float* __restrict__ A, int lda,
                                const float* __restrict__ Bm, int ldb,
                                int m0, int n0, int K,
                                float acc[4][4], float* As, float* Bs)
{
    const int tid = threadIdx.x;
    const int tx = tid & 15, ty = tid >> 4;
    const int ar  = tid >> 3;     // 0..31 (+32 on second pass)
    const int akc = tid & 7;      // float4 index along k
    for (int k0 = 0; k0 < K; k0 += 32) {
        __syncthreads();   // separates previous compute from new staging
        // ---- stage A: 64 rows x 32 k, transpose-write to As[k][m]
        #pragma unroll
        for (int it = 0; it < 2; ++it) {
            const int r = ar + it * 32;
            const float4 a4 = *(const float4*)&A[(m0 + r) * lda + k0 + akc * 4];
            As[(akc * 4 + 0) * 68 + r] = a4.x;
            As[(akc * 4 + 1) * 68 + r] = a4.y;
            As[(akc * 4 + 2) * 68 + r] = a4.z;
            As[(akc * 4 + 3) * 68 + r] = a4.w;
        }
        // ---- stage B
        if constexpr (BT) {
            #pragma unroll
            for (int it = 0; it < 2; ++it) {
                const int n = ar + it * 32;
                const float4 b4 = *(const float4*)&Bm[(n0 + n) * ldb + k0 + akc * 4];
                Bs[(akc * 4 + 0) * 68 + n] = b4.x;
                Bs[(akc * 4 + 1) * 68 + n] = b4.y;
                Bs[(akc * 4 + 2) * 68 + n] = b4.z;
                Bs[(akc * 4 + 3) * 68 + n] = b4.w;
            }
        } else {
            const int bn4 = tid & 15;   // n = bn4*4
            const int bk  = tid >> 4;   // 0..15 (+16 on second pass)
            #pragma unroll
            for (int it = 0; it < 2; ++it) {
                const int kk = bk + it * 16;
                *(float4*)&Bs[kk * 68 + bn4 * 4] =
                    *(const float4*)&Bm[(k0 + kk) * ldb + n0 + bn4 * 4];
            }
        }
        __syncthreads();
        // ---- compute: 32 k-steps, both operands b128
        #pragma unroll
        for (int kk = 0; kk < 32; ++kk) {
            const float4 a4 = *(const float4*)&As[kk * 68 + ty * 4];
            const float4 b4 = *(const float4*)&Bs[kk * 68 + tx * 4];
            const float av[4] = {a4.x, a4.y, a4.z, a4.w};
            const float bw[4] = {b4.x, b4.y, b4.z, b4.w};
            #pragma unroll
            for (int i = 0; i < 4; ++i)
                #pragma unroll
                for (int j = 0; j < 4; ++j)
                    acc[i][j] = __builtin_fmaf(av[i], bw[j], acc[i][j]);
        }
    }
}

// C = alpha * S @ S^T + EPS*I   (n x n, n multiple of 64)
__global__ __launch_bounds__(256) void k_gemm_sym(const float* __restrict__ S,
                                                  float* __restrict__ C,
                                                  int n, float alpha)
{
    __shared__ __align__(16) float As[32 * 68];
    __shared__ __align__(16) float Bs[32 * 68];
    float acc[4][4] = {};
    const int m0 = blockIdx.y * 64, n0 = blockIdx.x * 64;
    gemm_seg<true>(S, n, S, n, m0, n0, n, acc, As, Bs);
    const int tx = threadIdx.x & 15, ty = threadIdx.x >> 4;
    #pragma unroll
    for (int i = 0; i < 4; ++i)
        #pragma unroll
        for (int j = 0; j < 4; ++j) {
            int r = m0 + ty * 4 + i, c = n0 + tx * 4 + j;
            float v = alpha * acc[i][j];
            if (r == c) v += EPSc;
            C[r * n + c] = v;
        }
}

// From H (512x512), Chi, Y1: build YM = [Y | M] (256x512), D11 (256x256), linv (256)
__global__ void k_derive(const float* __restrict__ H, const float* __restrict__ Chi,
                         const float* __restrict__ Y1,
                         float* __restrict__ YM, float* __restrict__ D11,
                         float* __restrict__ linv)
{
    const int i = blockIdx.x;
    const int j = threadIdx.x;
    const float li = 2.0f / H[(256 + i) * 512 + 256 + i];
    YM[i * 512 + j] = -0.5f * (H[i * 512 + j] + Y1[i * 256 + j] - Y1[j * 256 + i]);
    YM[i * 512 + 256 + j] = -H[i * 512 + 256 + j] - Chi[i * 256 + j];
    D11[i * 256 + j] = (j < i) ? (-H[(256 + i) * 512 + 256 + j] * li) : 0.0f;
    if (j == 0) linv[i] = li;
}

// base = (xi @ Chi) * linv[col] + u @ D12^T + bv    -> basew (8192 x 256)
__global__ __launch_bounds__(256) void k_base(const float* __restrict__ xi,
                                              const float* __restrict__ u,
                                              const float* __restrict__ Chi,
                                              const float* __restrict__ D12,
                                              const float* __restrict__ bv,
                                              const float* __restrict__ linv,
                                              float* __restrict__ basew)
{
    __shared__ __align__(16) float As[32 * 68];
    __shared__ __align__(16) float Bs[32 * 68];
    float acc[4][4] = {};
    const int m0 = blockIdx.y * 64, n0 = blockIdx.x * 64;
    gemm_seg<false>(xi, 256, Chi, 256, m0, n0, 256, acc, As, Bs);
    const int tx = threadIdx.x & 15, ty = threadIdx.x >> 4;
    #pragma unroll
    for (int j = 0; j < 4; ++j) {
        float lv = linv[n0 + tx * 4 + j];
        #pragma unroll
        for (int i = 0; i < 4; ++i) acc[i][j] *= lv;
    }
    gemm_seg<true>(u, 128, D12, 128, m0, n0, 128, acc, As, Bs);
    #pragma unroll
    for (int i = 0; i < 4; ++i)
        #pragma unroll
        for (int j = 0; j < 4; ++j) {
            int r = m0 + ty * 4 + i, c = n0 + tx * 4 + j;
            basew[r * 256 + c] = acc[i][j] + bv[c];
        }
}

// ---------------------------------------------------------------------------
// In-place Gauss-Jordan inverse of 256x256 SPD matrix (no pivoting).
// Column-cyclic ownership; pivot column via __shfl; 1 barrier/step.
// ---------------------------------------------------------------------------
__global__ __launch_bounds__(1024) void k_gj(float* __restrict__ M)
{
    __shared__ float prbuf[2][256];
    const int tid = threadIdx.x;
    const int tx = tid & 31;
    const int ty = tid >> 5;
    float m[8][8];
    #pragma unroll
    for (int ii = 0; ii < 8; ++ii)
        #pragma unroll
        for (int jj = 0; jj < 8; ++jj)
            m[ii][jj] = M[(ty * 8 + ii) * 256 + tx + 32 * jj];

    if (ty == 0) {
        #pragma unroll
        for (int jj = 0; jj < 8; ++jj) prbuf[0][tx + 32 * jj] = m[0][jj];
    }
    __syncthreads();

    #pragma unroll
    for (int kj = 0; kj < 8; ++kj) {
        #pragma unroll 1
        for (int kt = 0; kt < 32; ++kt) {
            const int k = kj * 32 + kt;
            const float* pr = prbuf[k & 1];
            float* prn = prbuf[(k + 1) & 1];
            const float pinv = 1.0f / pr[k];
            const int srcLane = (tid & 32) | kt;
            float prv[8], pcv[8];
            #pragma unroll
            for (int jj = 0; jj < 8; ++jj) prv[jj] = pr[tx + 32 * jj];
            #pragma unroll
            for (int ii = 0; ii < 8; ++ii) pcv[ii] = __shfl(m[ii][kj], srcLane);
            const bool colown = (tx == kt);
            #pragma unroll
            for (int ii = 0; ii < 8; ++ii) {
                const float fi = pcv[ii] * pinv;
                #pragma unroll
                for (int jj = 0; jj < 8; ++jj)
                    m[ii][jj] = __builtin_fmaf(-fi, prv[jj], m[ii][jj]);
                if (colown) m[ii][kj] = -fi;
            }
            if (ty == (k >> 3)) {          // row-k owner: patch pivot row
                const int kl = k & 7;
                #pragma unroll
                for (int ii = 0; ii < 8; ++ii) if (ii == kl) {
                    #pragma unroll
                    for (int jj = 0; jj < 8; ++jj) m[ii][jj] = prv[jj] * pinv;
                    if (colown) m[ii][kj] = pinv;
                }
            }
            if (ty == ((k + 1) >> 3)) {    // stage next pivot row (updated)
                const int kl1 = (k + 1) & 7;
                #pragma unroll
                for (int ii = 0; ii < 8; ++ii) if (ii == kl1) {
                    #pragma unroll
                    for (int jj = 0; jj < 8; ++jj) prn[tx + 32 * jj] = m[ii][jj];
                }
            }
            __syncthreads();
        }
    }

    #pragma unroll
    for (int ii = 0; ii < 8; ++ii)
        #pragma unroll
        for (int jj = 0; jj < 8; ++jj)
            M[(ty * 8 + ii) * 256 + tx + 32 * jj] = m[ii][jj];
}

// ---------------------------------------------------------------------------
// Blocked nonlinear forward substitution (v3, right-looking serial phase):
//   w[:,i] = tanh(base[:,i] + sum_{j<i} w[:,j]*D11[i][j])
// 32 batch-rows/block, 4 waves; each wave owns 8 rows (lanes: rg=row, t=col%8).
// Per 32-column block c:
//   - stage D11 diag block [i0..i0+31]^2 into LDS dblk (pad 33)
//   - dense left-looking history: acc[u] = base + sum_{j<i0} w_j D11[i_u][j]
//   - serial right-looking: per step, tanh -> 1 shfl broadcast -> off-chain
//     FMA updates of FUTURE accs from dblk. Chain = tanh + shfl + fma only;
//     no LDS/global reads on the chain.
// ---------------------------------------------------------------------------
#define WPAD 264
__global__ __launch_bounds__(256) void k_scan(const float* __restrict__ d11,
                                              float* __restrict__ basew)
{
    __shared__ __align__(16) float wls[32 * WPAD];
    __shared__ __align__(16) float dblk[32 * 33];
    const int tid = threadIdx.x;
    const int row0 = blockIdx.x * 32;
    for (int idx = tid; idx < 32 * 64; idx += 256) {
        int r = idx >> 6, c4 = idx & 63;
        *(float4*)&wls[r * WPAD + c4 * 4] =
            *(const float4*)&basew[(row0 + r) * 256 + c4 * 4];
    }
    __syncthreads();

    const int lane = tid & 63;
    const int wv = tid >> 6;
    const int t = lane & 7;            // owns i with (i & 7) == t
    const int rg = lane >> 3;          // row within wave
    const int r = wv * 8 + rg;
    float* rowp = &wls[r * WPAD];
    const int sr = tid >> 3, sc4 = tid & 7;   // dblk staging coords

    #pragma unroll 1
    for (int c = 0; c < 8; ++c) {
        const int i0 = 32 * c;
        // ---- stage D11 diagonal 32x32 block (1 float4/thread); completes
        //      during the dense phase, consumed after the barrier.
        const float4 dv4 = *(const float4*)&d11[(i0 + sr) * 256 + i0 + sc4 * 4];
        dblk[sr * 33 + sc4 * 4 + 0] = dv4.x;
        dblk[sr * 33 + sc4 * 4 + 1] = dv4.y;
        dblk[sr * 33 + sc4 * 4 + 2] = dv4.z;
        dblk[sr * 33 + sc4 * 4 + 3] = dv4.w;
        // ---- dense history: acc[u] = sum_{j<i0} w[j] * D11[i0+8u+t][j]
        float acc[4] = {0.f, 0.f, 0.f, 0.f};
        {
            const float* d0 = d11 + (i0 + t) * 256;
            for (int j = 0; j < i0; j += 4) {
                const float4 w4 = *(const float4*)&rowp[j];
                #pragma unroll
                for (int u = 0; u < 4; ++u) {
                    const float4 dv = *(const float4*)&d0[u * 8 * 256 + j];
                    acc[u] = __builtin_fmaf(w4.x, dv.x, acc[u]);
                    acc[u] = __builtin_fmaf(w4.y, dv.y, acc[u]);
                    acc[u] = __builtin_fmaf(w4.z, dv.z, acc[u]);
                    acc[u] = __builtin_fmaf(w4.w, dv.w, acc[u]);
                }
            }
        }
        // ---- add base for owned columns (LDS, off-chain)
        #pragma unroll
        for (int u = 0; u < 4; ++u) acc[u] += rowp[i0 + 8 * u + t];
        __syncthreads();              // dblk staged by all threads
        // ---- serial right-looking: 32 steps, chain = tanh -> shfl -> fma
        #pragma unroll
        for (int jj = 0; jj < 32; ++jj) {
            const int o = jj & 7, uo = jj >> 3;
            // all lanes compute tanh of their acc[uo]; only owner's is w_jj
            const float x = acc[uo];
            const float v = 1.0f - 2.0f / (__expf(2.0f * x) + 1.0f);
            const float wj = __shfl(v, o, 8);     // broadcast in 8-lane group
            if (t == o) rowp[i0 + jj] = v;        // off-chain store
            #pragma unroll
            for (int u = 0; u < 4; ++u) {
                if (8 * u + t > jj)               // future owned columns only
                    acc[u] = __builtin_fmaf(wj, dblk[(8 * u + t) * 33 + jj], acc[u]);
            }
        }
        __syncthreads();              // dblk free for next c
    }

    __syncthreads();
    for (int idx = tid; idx < 32 * 64; idx += 256) {
        int rr = idx >> 6, c4 = idx & 63;
        *(float4*)&basew[(row0 + rr) * 256 + c4 * 4] =
            *(const float4*)&wls[rr * WPAD + c4 * 4];
    }
}

// AB = Pinv @ [Y | M]   (256 x 512): rows give A[x][k] and B1[x][q] directly
__global__ __launch_bounds__(256) void k_ab(const float* __restrict__ Pinv,
                                            const float* __restrict__ YM,
                                            float* __restrict__ AB)
{
    __shared__ __align__(16) float As[32 * 68];
    __shared__ __align__(16) float Bs[32 * 68];
    float acc[4][4] = {};
    const int m0 = blockIdx.y * 64, n0 = blockIdx.x * 64;
    gemm_seg<false>(Pinv, 256, YM, 512, m0, n0, 256, acc, As, Bs);
    const int tx = threadIdx.x & 15, ty = threadIdx.x >> 4;
    #pragma unroll
    for (int i = 0; i < 4; ++i)
        #pragma unroll
        for (int j = 0; j < 4; ++j)
            AB[(m0 + ty * 4 + i) * 512 + n0 + tx * 4 + j] = acc[i][j];
}

// xi_dot = xi @ A^T + w @ B1^T + u @ B2^T + bx
__global__ __launch_bounds__(256) void k_final(const float* __restrict__ xi,
                                               const float* __restrict__ w,
                                               const float* __restrict__ u,
                                               const float* __restrict__ AB,
                                               const float* __restrict__ B2,
                                               const float* __restrict__ bx,
                                               float* __restrict__ out)
{
    __shared__ __align__(16) float As[32 * 68];
    __shared__ __align__(16) float Bs[32 * 68];
    float acc[4][4] = {};
    const int m0 = blockIdx.y * 64, n0 = blockIdx.x * 64;
    gemm_seg<true>(xi, 256, AB, 512, m0, n0, 256, acc, As, Bs);        // A-part
    gemm_seg<true>(w, 256, AB + 256, 512, m0, n0, 256, acc, As, Bs);   // B1-part
    gemm_seg<true>(u, 128, B2, 128, m0, n0, 128, acc, As, Bs);         // B2-part
    const int tx = threadIdx.x & 15, ty = threadIdx.x >> 4;
    #pragma unroll
    for (int i = 0; i < 4; ++i)
        #pragma unroll
        for (int j = 0; j < 4; ++j) {
            int r = m0 + ty * 4 + i, c = n0 + tx * 4 + j;
            out[r * 256 + c] = acc[i][j] + bx[c];
        }
}

extern "C" void kernel_launch(void* const* d_in, const int* in_sizes, int n_in,
                              void* d_out, int out_size, void* d_ws, size_t ws_size,
                              hipStream_t stream)
{
    (void)in_sizes; (void)n_in; (void)out_size; (void)ws_size;
    // setup_inputs order: t, xi, u, Pstar, Chi, Y1, B2, D12, X, bx, bv
    const float* xi    = (const float*)d_in[1];
    const float* u     = (const float*)d_in[2];
    const float* Pstar = (const float*)d_in[3];
    const float* Chi   = (const float*)d_in[4];
    const float* Y1    = (const float*)d_in[5];
    const float* B2    = (const float*)d_in[6];
    const float* D12   = (const float*)d_in[7];
    const float* X     = (const float*)d_in[8];
    const float* bx    = (const float*)d_in[9];
    const float* bv    = (const float*)d_in[10];
    float* out = (float*)d_out;

    float* ws    = (float*)d_ws;
    float* H     = ws;              // 512*512   = 262144
    float* YM    = H + 262144;      // 256*512   = 131072
    float* D11   = YM + 131072;     // 256*256   =  65536
    float* linv  = D11 + 65536;     // 256
    float* Pm    = linv + 256;      // 256*256   =  65536  (becomes Pinv)
    float* AB    = Pm + 65536;      // 256*512   = 131072
    float* basew = AB + 131072;     // 8192*256  = 2097152 (base, then w in-place)

    k_gemm_sym<<<dim3(8, 8), 256, 0, stream>>>(X, H, 512, 1.0f);         // H = X X^T + eps I
    k_gemm_sym<<<dim3(4, 4), 256, 0, stream>>>(Pstar, Pm, 256, 0.5f);    // P
    k_derive  <<<dim3(256), 256, 0, stream>>>(H, Chi, Y1, YM, D11, linv);
    k_base    <<<dim3(4, 128), 256, 0, stream>>>(xi, u, Chi, D12, bv, linv, basew);
    k_gj      <<<dim3(1), 1024, 0, stream>>>(Pm);                        // Pm -> Pinv
    k_scan    <<<dim3(256), 256, 0, stream>>>(D11, basew);               // basew -> w
    k_ab      <<<dim3(8, 4), 256, 0, stream>>>(Pm, YM, AB);              // [A | B1]
    k_final   <<<dim3(4, 128), 256, 0, stream>>>(xi, basew, u, AB, B2, bx, out);
}

// Round 6
// 390.236 us; speedup vs baseline: 7.1315x; 1.2630x over previous
//
#include <hip/hip_runtime.h>

// Sizes (fixed by the problem)
#define NXc 256
#define NQc 256
#define NUc 128
#define Bc  8192
#define NHc 512
#define EPSc 0.001f

// ---------------------------------------------------------------------------
// Tiled f32 GEMM segment v2: accumulates a 64x64 C-tile over K.
// Block = 256 threads (16x16), 4x4 micro-tile, BK=32.
// ---------------------------------------------------------------------------
template<bool BT>
__device__ inline void gemm_seg(const float* __restrict__ A, int lda,
                                const float* __restrict__ Bm, int ldb,
                                int m0, int n0, int K,
                                float acc[4][4], float* As, float* Bs)
{
    const int tid = threadIdx.x;
    const int tx = tid & 15, ty = tid >> 4;
    const int ar  = tid >> 3;     // 0..31 (+32 on second pass)
    const int akc = tid & 7;      // float4 index along k
    for (int k0 = 0; k0 < K; k0 += 32) {
        __syncthreads();   // separates previous compute from new staging
        #pragma unroll
        for (int it = 0; it < 2; ++it) {
            const int r = ar + it * 32;
            const float4 a4 = *(const float4*)&A[(m0 + r) * lda + k0 + akc * 4];
            As[(akc * 4 + 0) * 68 + r] = a4.x;
            As[(akc * 4 + 1) * 68 + r] = a4.y;
            As[(akc * 4 + 2) * 68 + r] = a4.z;
            As[(akc * 4 + 3) * 68 + r] = a4.w;
        }
        if constexpr (BT) {
            #pragma unroll
            for (int it = 0; it < 2; ++it) {
                const int n = ar + it * 32;
                const float4 b4 = *(const float4*)&Bm[(n0 + n) * ldb + k0 + akc * 4];
                Bs[(akc * 4 + 0) * 68 + n] = b4.x;
                Bs[(akc * 4 + 1) * 68 + n] = b4.y;
                Bs[(akc * 4 + 2) * 68 + n] = b4.z;
                Bs[(akc * 4 + 3) * 68 + n] = b4.w;
            }
        } else {
            const int bn4 = tid & 15;   // n = bn4*4
            const int bk  = tid >> 4;   // 0..15 (+16 on second pass)
            #pragma unroll
            for (int it = 0; it < 2; ++it) {
                const int kk = bk + it * 16;
                *(float4*)&Bs[kk * 68 + bn4 * 4] =
                    *(const float4*)&Bm[(k0 + kk) * ldb + n0 + bn4 * 4];
            }
        }
        __syncthreads();
        #pragma unroll
        for (int kk = 0; kk < 32; ++kk) {
            const float4 a4 = *(const float4*)&As[kk * 68 + ty * 4];
            const float4 b4 = *(const float4*)&Bs[kk * 68 + tx * 4];
            const float av[4] = {a4.x, a4.y, a4.z, a4.w};
            const float bw[4] = {b4.x, b4.y, b4.z, b4.w};
            #pragma unroll
            for (int i = 0; i < 4; ++i)
                #pragma unroll
                for (int j = 0; j < 4; ++j)
                    acc[i][j] = __builtin_fmaf(av[i], bw[j], acc[i][j]);
        }
    }
}

// C = alpha * S @ S^T + EPS*I   (n x n, n multiple of 64)
__global__ __launch_bounds__(256) void k_gemm_sym(const float* __restrict__ S,
                                                  float* __restrict__ C,
                                                  int n, float alpha)
{
    __shared__ __align__(16) float As[32 * 68];
    __shared__ __align__(16) float Bs[32 * 68];
    float acc[4][4] = {};
    const int m0 = blockIdx.y * 64, n0 = blockIdx.x * 64;
    gemm_seg<true>(S, n, S, n, m0, n0, n, acc, As, Bs);
    const int tx = threadIdx.x & 15, ty = threadIdx.x >> 4;
    #pragma unroll
    for (int i = 0; i < 4; ++i)
        #pragma unroll
        for (int j = 0; j < 4; ++j) {
            int r = m0 + ty * 4 + i, c = n0 + tx * 4 + j;
            float v = alpha * acc[i][j];
            if (r == c) v += EPSc;
            C[r * n + c] = v;
        }
}

// From H (512x512), Chi, Y1: build YM = [Y | M] (256x512), D11 (256x256), linv (256)
__global__ void k_derive(const float* __restrict__ H, const float* __restrict__ Chi,
                         const float* __restrict__ Y1,
                         float* __restrict__ YM, float* __restrict__ D11,
                         float* __restrict__ linv)
{
    const int i = blockIdx.x;
    const int j = threadIdx.x;
    const float li = 2.0f / H[(256 + i) * 512 + 256 + i];
    YM[i * 512 + j] = -0.5f * (H[i * 512 + j] + Y1[i * 256 + j] - Y1[j * 256 + i]);
    YM[i * 512 + 256 + j] = -H[i * 512 + 256 + j] - Chi[i * 256 + j];
    D11[i * 256 + j] = (j < i) ? (-H[(256 + i) * 512 + 256 + j] * li) : 0.0f;
    if (j == 0) linv[i] = li;
}

// base = (xi @ Chi) * linv[col] + u @ D12^T + bv    -> basew (8192 x 256)
__global__ __launch_bounds__(256) void k_base(const float* __restrict__ xi,
                                              const float* __restrict__ u,
                                              const float* __restrict__ Chi,
                                              const float* __restrict__ D12,
                                              const float* __restrict__ bv,
                                              const float* __restrict__ linv,
                                              float* __restrict__ basew)
{
    __shared__ __align__(16) float As[32 * 68];
    __shared__ __align__(16) float Bs[32 * 68];
    float acc[4][4] = {};
    const int m0 = blockIdx.y * 64, n0 = blockIdx.x * 64;
    gemm_seg<false>(xi, 256, Chi, 256, m0, n0, 256, acc, As, Bs);
    const int tx = threadIdx.x & 15, ty = threadIdx.x >> 4;
    #pragma unroll
    for (int j = 0; j < 4; ++j) {
        float lv = linv[n0 + tx * 4 + j];
        #pragma unroll
        for (int i = 0; i < 4; ++i) acc[i][j] *= lv;
    }
    gemm_seg<true>(u, 128, D12, 128, m0, n0, 128, acc, As, Bs);
    #pragma unroll
    for (int i = 0; i < 4; ++i)
        #pragma unroll
        for (int j = 0; j < 4; ++j) {
            int r = m0 + ty * 4 + i, c = n0 + tx * 4 + j;
            basew[r * 256 + c] = acc[i][j] + bv[c];
        }
}

// ---------------------------------------------------------------------------
// GJ body: in-place Gauss-Jordan inverse of 256x256 SPD matrix (no pivoting).
// 1024 threads. Column-cyclic ownership; pivot column via __shfl; 1 barrier/step.
// prbuf: 2*256 floats of LDS provided by caller.
// ---------------------------------------------------------------------------
__device__ void gj_body(float* __restrict__ M, float* __restrict__ prbuf_raw)
{
    float (*prbuf)[256] = (float (*)[256])prbuf_raw;
    const int tid = threadIdx.x;
    const int tx = tid & 31;
    const int ty = tid >> 5;
    float m[8][8];
    #pragma unroll
    for (int ii = 0; ii < 8; ++ii)
        #pragma unroll
        for (int jj = 0; jj < 8; ++jj)
            m[ii][jj] = M[(ty * 8 + ii) * 256 + tx + 32 * jj];

    if (ty == 0) {
        #pragma unroll
        for (int jj = 0; jj < 8; ++jj) prbuf[0][tx + 32 * jj] = m[0][jj];
    }
    __syncthreads();

    #pragma unroll
    for (int kj = 0; kj < 8; ++kj) {
        #pragma unroll 1
        for (int kt = 0; kt < 32; ++kt) {
            const int k = kj * 32 + kt;
            const float* pr = prbuf[k & 1];
            float* prn = prbuf[(k + 1) & 1];
            const float pinv = 1.0f / pr[k];
            const int srcLane = (tid & 32) | kt;
            float prv[8], pcv[8];
            #pragma unroll
            for (int jj = 0; jj < 8; ++jj) prv[jj] = pr[tx + 32 * jj];
            #pragma unroll
            for (int ii = 0; ii < 8; ++ii) pcv[ii] = __shfl(m[ii][kj], srcLane);
            const bool colown = (tx == kt);
            #pragma unroll
            for (int ii = 0; ii < 8; ++ii) {
                const float fi = pcv[ii] * pinv;
                #pragma unroll
                for (int jj = 0; jj < 8; ++jj)
                    m[ii][jj] = __builtin_fmaf(-fi, prv[jj], m[ii][jj]);
                if (colown) m[ii][kj] = -fi;
            }
            if (ty == (k >> 3)) {          // row-k owner: patch pivot row
                const int kl = k & 7;
                #pragma unroll
                for (int ii = 0; ii < 8; ++ii) if (ii == kl) {
                    #pragma unroll
                    for (int jj = 0; jj < 8; ++jj) m[ii][jj] = prv[jj] * pinv;
                    if (colown) m[ii][kj] = pinv;
                }
            }
            if (ty == ((k + 1) >> 3)) {    // stage next pivot row (updated)
                const int kl1 = (k + 1) & 7;
                #pragma unroll
                for (int ii = 0; ii < 8; ++ii) if (ii == kl1) {
                    #pragma unroll
                    for (int jj = 0; jj < 8; ++jj) prn[tx + 32 * jj] = m[ii][jj];
                }
            }
            __syncthreads();
        }
    }

    #pragma unroll
    for (int ii = 0; ii < 8; ++ii)
        #pragma unroll
        for (int jj = 0; jj < 8; ++jj)
            M[(ty * 8 + ii) * 256 + tx + 32 * jj] = m[ii][jj];
}

// ---------------------------------------------------------------------------
// Scan body (right-looking blocked nonlinear forward substitution), executed
// by a 1024-thread block with 256 working threads (others ride the barriers).
//   w[:,i] = tanh(base[:,i] + sum_{j<i} w[:,j]*D11[i][j])
// wls: 32*WPAD floats; dblk: 32*33 floats (caller-provided LDS).
// ---------------------------------------------------------------------------
#define WPAD 264
__device__ void scan_body(const float* __restrict__ d11,
                          float* __restrict__ basew, int blk,
                          float* __restrict__ wls, float* __restrict__ dblk)
{
    const int tid = threadIdx.x;
    const int row0 = blk * 32;
    // load: all 1024 threads, 2 float4 each
    for (int idx = tid; idx < 32 * 64; idx += 1024) {
        int r = idx >> 6, c4 = idx & 63;
        *(float4*)&wls[r * WPAD + c4 * 4] =
            *(const float4*)&basew[(row0 + r) * 256 + c4 * 4];
    }
    __syncthreads();

    const bool act = (tid < 256);
    const int lane = tid & 63;
    const int t = lane & 7;            // owns i with (i & 7) == t
    const int rg = lane >> 3;          // row within wave
    const int r = (tid >> 6) * 8 + rg;
    float* rowp = act ? &wls[r * WPAD] : &wls[0];
    const int sr = tid >> 3, sc4 = tid & 7;   // dblk staging coords (tid<256)

    #pragma unroll 1
    for (int c = 0; c < 8; ++c) {
        const int i0 = 32 * c;
        float acc[4] = {0.f, 0.f, 0.f, 0.f};
        if (act) {
            // stage D11 diagonal 32x32 block (1 float4/thread, tid<256)
            const float4 dv4 = *(const float4*)&d11[(i0 + sr) * 256 + i0 + sc4 * 4];
            dblk[sr * 33 + sc4 * 4 + 0] = dv4.x;
            dblk[sr * 33 + sc4 * 4 + 1] = dv4.y;
            dblk[sr * 33 + sc4 * 4 + 2] = dv4.z;
            dblk[sr * 33 + sc4 * 4 + 3] = dv4.w;
            // dense history: acc[u] = sum_{j<i0} w[j] * D11[i0+8u+t][j]
            const float* d0 = d11 + (i0 + t) * 256;
            for (int j = 0; j < i0; j += 4) {
                const float4 w4 = *(const float4*)&rowp[j];
                #pragma unroll
                for (int u = 0; u < 4; ++u) {
                    const float4 dv = *(const float4*)&d0[u * 8 * 256 + j];
                    acc[u] = __builtin_fmaf(w4.x, dv.x, acc[u]);
                    acc[u] = __builtin_fmaf(w4.y, dv.y, acc[u]);
                    acc[u] = __builtin_fmaf(w4.z, dv.z, acc[u]);
                    acc[u] = __builtin_fmaf(w4.w, dv.w, acc[u]);
                }
            }
            #pragma unroll
            for (int u = 0; u < 4; ++u) acc[u] += rowp[i0 + 8 * u + t];
        }
        __syncthreads();              // dblk staged
        if (act) {
            // serial right-looking: 32 steps, chain = tanh -> shfl -> fma
            #pragma unroll
            for (int jj = 0; jj < 32; ++jj) {
                const int o = jj & 7, uo = jj >> 3;
                const float x = acc[uo];
                const float v = 1.0f - 2.0f / (__expf(2.0f * x) + 1.0f);
                const float wj = __shfl(v, o, 8);     // broadcast in 8-lane group
                if (t == o) rowp[i0 + jj] = v;        // off-chain store
                #pragma unroll
                for (int u = 0; u < 4; ++u) {
                    if (8 * u + t > jj)               // future owned columns only
                        acc[u] = __builtin_fmaf(wj, dblk[(8 * u + t) * 33 + jj], acc[u]);
                }
            }
        }
        __syncthreads();              // dblk free for next c
    }

    for (int idx = tid; idx < 32 * 64; idx += 1024) {
        int rr = idx >> 6, c4 = idx & 63;
        *(float4*)&basew[(row0 + rr) * 256 + c4 * 4] =
            *(const float4*)&wls[rr * WPAD + c4 * 4];
    }
}

// ---------------------------------------------------------------------------
// Fat kernel: block 0 runs the 1-CU Gauss-Jordan inverse while blocks 1..256
// run the scan on the other CUs. Barriers are per-block, so the two bodies
// need no coordination; they touch disjoint buffers.
// ---------------------------------------------------------------------------
__global__ __launch_bounds__(1024) void k_fat(float* __restrict__ Pm,
                                              const float* __restrict__ d11,
                                              float* __restrict__ basew)
{
    __shared__ __align__(16) float shmem[32 * WPAD + 32 * 33];
    if (blockIdx.x == 0) {
        gj_body(Pm, shmem);                       // uses 2*256 floats
    } else {
        scan_body(d11, basew, blockIdx.x - 1, shmem, shmem + 32 * WPAD);
    }
}

// AB = Pinv @ [Y | M]   (256 x 512): rows give A[x][k] and B1[x][q] directly
__global__ __launch_bounds__(256) void k_ab(const float* __restrict__ Pinv,
                                            const float* __restrict__ YM,
                                            float* __restrict__ AB)
{
    __shared__ __align__(16) float As[32 * 68];
    __shared__ __align__(16) float Bs[32 * 68];
    float acc[4][4] = {};
    const int m0 = blockIdx.y * 64, n0 = blockIdx.x * 64;
    gemm_seg<false>(Pinv, 256, YM, 512, m0, n0, 256, acc, As, Bs);
    const int tx = threadIdx.x & 15, ty = threadIdx.x >> 4;
    #pragma unroll
    for (int i = 0; i < 4; ++i)
        #pragma unroll
        for (int j = 0; j < 4; ++j)
            AB[(m0 + ty * 4 + i) * 512 + n0 + tx * 4 + j] = acc[i][j];
}

// xi_dot = xi @ A^T + w @ B1^T + u @ B2^T + bx
__global__ __launch_bounds__(256) void k_final(const float* __restrict__ xi,
                                               const float* __restrict__ w,
                                               const float* __restrict__ u,
                                               const float* __restrict__ AB,
                                               const float* __restrict__ B2,
                                               const float* __restrict__ bx,
                                               float* __restrict__ out)
{
    __shared__ __align__(16) float As[32 * 68];
    __shared__ __align__(16) float Bs[32 * 68];
    float acc[4][4] = {};
    const int m0 = blockIdx.y * 64, n0 = blockIdx.x * 64;
    gemm_seg<true>(xi, 256, AB, 512, m0, n0, 256, acc, As, Bs);        // A-part
    gemm_seg<true>(w, 256, AB + 256, 512, m0, n0, 256, acc, As, Bs);   // B1-part
    gemm_seg<true>(u, 128, B2, 128, m0, n0, 128, acc, As, Bs);         // B2-part
    const int tx = threadIdx.x & 15, ty = threadIdx.x >> 4;
    #pragma unroll
    for (int i = 0; i < 4; ++i)
        #pragma unroll
        for (int j = 0; j < 4; ++j) {
            int r = m0 + ty * 4 + i, c = n0 + tx * 4 + j;
            out[r * 256 + c] = acc[i][j] + bx[c];
        }
}

extern "C" void kernel_launch(void* const* d_in, const int* in_sizes, int n_in,
                              void* d_out, int out_size, void* d_ws, size_t ws_size,
                              hipStream_t stream)
{
    (void)in_sizes; (void)n_in; (void)out_size; (void)ws_size;
    // setup_inputs order: t, xi, u, Pstar, Chi, Y1, B2, D12, X, bx, bv
    const float* xi    = (const float*)d_in[1];
    const float* u     = (const float*)d_in[2];
    const float* Pstar = (const float*)d_in[3];
    const float* Chi   = (const float*)d_in[4];
    const float* Y1    = (const float*)d_in[5];
    const float* B2    = (const float*)d_in[6];
    const float* D12   = (const float*)d_in[7];
    const float* X     = (const float*)d_in[8];
    const float* bx    = (const float*)d_in[9];
    const float* bv    = (const float*)d_in[10];
    float* out = (float*)d_out;

    float* ws    = (float*)d_ws;
    float* H     = ws;              // 512*512   = 262144
    float* YM    = H + 262144;      // 256*512   = 131072
    float* D11   = YM + 131072;     // 256*256   =  65536
    float* linv  = D11 + 65536;     // 256
    float* Pm    = linv + 256;      // 256*256   =  65536  (becomes Pinv)
    float* AB    = Pm + 65536;      // 256*512   = 131072
    float* basew = AB + 131072;     // 8192*256  = 2097152 (base, then w in-place)

    k_gemm_sym<<<dim3(8, 8), 256, 0, stream>>>(X, H, 512, 1.0f);         // H
    k_gemm_sym<<<dim3(4, 4), 256, 0, stream>>>(Pstar, Pm, 256, 0.5f);    // P
    k_derive  <<<dim3(256), 256, 0, stream>>>(H, Chi, Y1, YM, D11, linv);
    k_base    <<<dim3(4, 128), 256, 0, stream>>>(xi, u, Chi, D12, bv, linv, basew);
    k_fat     <<<dim3(257), 1024, 0, stream>>>(Pm, D11, basew);          // GJ || scan
    k_ab      <<<dim3(8, 4), 256, 0, stream>>>(Pm, YM, AB);              // [A | B1]
    k_final   <<<dim3(4, 128), 256, 0, stream>>>(xi, basew, u, AB, B2, bx, out);
}